// Round 1
// baseline (203.030 us; speedup 1.0000x reference)
//
#include <hip/hip_runtime.h>
#include <math.h>

typedef __bf16 bf16;
typedef __bf16 bf16x4 __attribute__((ext_vector_type(4)));
typedef __bf16 bf16x8 __attribute__((ext_vector_type(8)));
typedef float f32x4 __attribute__((ext_vector_type(4)));

#define MFMA(a, b, c) __builtin_amdgcn_mfma_f32_16x16x32_bf16(a, b, c, 0, 0, 0)
#define LOG2E 1.44269504088896340736f

// XOR-swizzled 64x64 bf16 tile (8 KB): elem (row, chunk8) at row*64 + ((ch^(row&7))*8).
// R7: staged via global_load_lds width=16 — linear LDS dest, inverse-swizzled global
// source (rule #21: XOR is an involution, so frag() reads are unchanged). Removes the
// VGPR round trip + staging VALU entirely.
__device__ __forceinline__ void stage_async(bf16* __restrict__ T, const bf16* __restrict__ src,
                                            int rs, int t) {
#pragma unroll
    for (int i = 0; i < 2; ++i) {
        int u = i * 256 + t;                 // 16B chunk index in [0,512)
        int row = u >> 3, ch = u & 7;
        const bf16* g = src + (size_t)row * rs + ((ch ^ (row & 7)) << 3);
        bf16* lp = T + (size_t)(i * 256 + (t & 192)) * 8;   // wave-uniform base; HW adds lane*16
        __builtin_amdgcn_global_load_lds((__attribute__((address_space(1))) void*)g,
                                         (__attribute__((address_space(3))) void*)lp,
                                         16, 0, 0);
    }
}
__device__ __forceinline__ bf16x8 frag(const bf16* __restrict__ T, int row, int ch) {
    return *(const bf16x8*)&T[row * 64 + ((ch ^ (row & 7)) << 3)];
}

// ---------------- fused preprocessing (R6) ----------------
__global__ __launch_bounds__(256) void prep(
    const int* __restrict__ seqm, const int* __restrict__ spm,
    const float* __restrict__ x,
    const float* __restrict__ Wq, const float* __restrict__ Wk,
    const float* __restrict__ Wv, const float* __restrict__ Wo,
    unsigned* __restrict__ pseq, unsigned* __restrict__ psp,
    bf16* __restrict__ xb, bf16* __restrict__ Wb,
    bf16* __restrict__ Woh, bf16* __restrict__ Wol)
{
    int bid = blockIdx.x, t = threadIdx.x;
    if (bid < 2048) {
        int wave = t >> 6, lane = t & 63;
        int row = bid * 4 + wave;
        const int* src = (row < 4096) ? (seqm + (size_t)row * 2048)
                                      : (spm + (size_t)(row - 4096) * 2048);
        unsigned* dst = (row < 4096) ? (pseq + (size_t)row * 64)
                                     : (psp + (size_t)(row - 4096) * 64);
        unsigned myw = 0;
#pragma unroll
        for (int u = 0; u < 32; ++u) {
            int v = src[u * 64 + lane];
            unsigned long long bal = __ballot(v != 0);
            if ((lane >> 1) == u)
                myw = (lane & 1) ? (unsigned)(bal >> 32) : (unsigned)bal;
        }
        dst[lane] = myw;
    } else if (bid < 3072) {
        int i = ((bid - 2048) * 256 + t) * 8;
        float4 a = *(const float4*)&x[i];
        float4 c = *(const float4*)&x[i + 4];
        float v[8] = {a.x, a.y, a.z, a.w, c.x, c.y, c.z, c.w};
        bf16x8 o;
#pragma unroll
        for (int u = 0; u < 8; ++u) o[u] = (bf16)v[u];
        *(bf16x8*)&xb[i] = o;
    } else {
        int zb = bid - 3072;
        int z = zb >> 7;
        int i = ((zb & 127) * 256 + t) * 8;
        const float* src = (z == 0) ? Wq : (z == 1) ? Wk : (z == 2) ? Wv : Wo;
        float4 a = *(const float4*)&src[i];
        float4 c = *(const float4*)&src[i + 4];
        float v[8] = {a.x, a.y, a.z, a.w, c.x, c.y, c.z, c.w};
        if (z < 3) {
            bf16x8 o;
#pragma unroll
            for (int u = 0; u < 8; ++u) o[u] = (bf16)v[u];
            *(bf16x8*)&Wb[(size_t)z * 262144 + i] = o;
        } else {
            bf16x8 oh, ol;
#pragma unroll
            for (int u = 0; u < 8; ++u) {
                bf16 hi = (bf16)v[u];
                oh[u] = hi;
                ol[u] = (bf16)(v[u] - (float)hi);
            }
            *(bf16x8*)&Woh[i] = oh;
            *(bf16x8*)&Wol[i] = ol;
        }
    }
}

// ---------------- fused QKV projection, 64x128 tiles ----------------
// grid 768 = m0b(64, XCD-sticky) x np(4) x z(3). R7: async LDS staging.
__global__ __launch_bounds__(256) void gemm_qkv(
    const bf16* __restrict__ A, const bf16* __restrict__ Wb,
    bf16* __restrict__ Qg, bf16* __restrict__ Kg, bf16* __restrict__ Vt)
{
    __shared__ bf16 AT[4096], WT0[4096], WT1[4096];
    __shared__ bf16 Lt[64 * 72];
    int bid = blockIdx.x;
    int m0b = bid & 63;
    int rest = bid >> 6;
    int np = rest & 3, z = rest >> 2;
    const bf16* W = Wb + (size_t)z * 262144;
    float scale = (z == 0) ? (0.125f * LOG2E) : 1.0f;

    int t = threadIdx.x, wave = t >> 6, lane = t & 63, l = lane & 15, quad = lane >> 4;
    int m0 = m0b * 64 + wave * 16;
    int nb = np * 128;
    f32x4 acc[8] = {};
    for (int k0 = 0; k0 < 512; k0 += 64) {
        __syncthreads();
        stage_async(AT, A + (size_t)m0b * 64 * 512 + k0, 512, t);
        stage_async(WT0, W + (size_t)nb * 512 + k0, 512, t);
        stage_async(WT1, W + (size_t)(nb + 64) * 512 + k0, 512, t);
        __syncthreads();
        bf16x8 a0 = frag(AT, wave * 16 + l, quad);
        bf16x8 a1 = frag(AT, wave * 16 + l, 4 + quad);
#pragma unroll
        for (int nc = 0; nc < 4; ++nc) {
            bf16x8 b0 = frag(WT0, nc * 16 + l, quad);
            bf16x8 b1 = frag(WT0, nc * 16 + l, 4 + quad);
            acc[nc] = MFMA(a0, b0, acc[nc]);
            acc[nc] = MFMA(a1, b1, acc[nc]);
        }
#pragma unroll
        for (int nc = 0; nc < 4; ++nc) {
            bf16x8 b0 = frag(WT1, nc * 16 + l, quad);
            bf16x8 b1 = frag(WT1, nc * 16 + l, 4 + quad);
            acc[4 + nc] = MFMA(a0, b0, acc[4 + nc]);
            acc[4 + nc] = MFMA(a1, b1, acc[4 + nc]);
        }
    }
    if (z < 2) {
        bf16* out = (z == 0) ? Qg : Kg;
#pragma unroll
        for (int nc = 0; nc < 8; ++nc) {
#pragma unroll
            for (int r = 0; r < 4; ++r) {
                int m = m0 + quad * 4 + r;
                int feat = nb + nc * 16 + l;
                int b = m >> 11, tok = m & 2047, h = feat >> 6, d = feat & 63;
                out[(((size_t)(b * 8 + h)) * 2048 + tok) * 64 + d] = (bf16)(acc[nc][r] * scale);
            }
        }
    } else {
#pragma unroll
        for (int hh = 0; hh < 2; ++hh) {
            __syncthreads();
#pragma unroll
            for (int nc = 0; nc < 4; ++nc)
#pragma unroll
                for (int r = 0; r < 4; ++r)
                    Lt[(nc * 16 + l) * 72 + wave * 16 + quad * 4 + r] = (bf16)acc[hh * 4 + nc][r];
            __syncthreads();
            int d = t >> 2, seg = t & 3;
            int tok0 = m0b * 64;
            int b = tok0 >> 11, h = np * 2 + hh;
            bf16x8 o0, o1;
#pragma unroll
            for (int i = 0; i < 8; ++i) { o0[i] = Lt[d * 72 + seg * 16 + i]; o1[i] = Lt[d * 72 + seg * 16 + 8 + i]; }
            size_t base = ((size_t)(b * 8 + h) * 64 + d) * 2048 + (tok0 & 2047) + seg * 16;
            *(bf16x8*)&Vt[base] = o0;
            *(bf16x8*)&Vt[base + 8] = o1;
        }
    }
}

// ---------------- flash attention (R7): 128 q-rows/block, async staging ----------------
// grid 1024 = jc(2b) | itp(4b) | bh(4b); 4 waves; LDS 25.6 KB.
// Two 64-row q-subtiles share K/V staging, barriers, and K/V frag reads (2x intensity
// per staged tile). P LDS buffer reused sequentially (same-wave DS is in-order).
// All 1024 blocks co-resident at 4 blocks/CU -> single dispatch round.
__global__ __launch_bounds__(256, 4) void attn_kernel(
    const bf16* __restrict__ Qg, const bf16* __restrict__ Kg, const bf16* __restrict__ Vt,
    const unsigned* __restrict__ pseq, const unsigned* __restrict__ psp,
    float* __restrict__ Opart, float* __restrict__ Lpart)
{
    __shared__ bf16 KT[4096], VT[4096];
    __shared__ bf16 P[4 * 16 * 72];
    int bid = blockIdx.x;
    int bh = bid & 15;                       // XCD = bid%8 -> K/V L2-resident
    int itp = (bid >> 4) & 15;
    int jc = bid >> 8;
    int i0 = itp * 128;
    int b = bh >> 3, par = bh & 1;
    int t = threadIdx.x, rg = t >> 6, lane = t & 63, l = lane & 15, quad = lane >> 4;

    const bf16* QpA = Qg + ((size_t)bh * 2048 + i0 + rg * 16 + l) * 64;
    bf16x8 qa0 = *(const bf16x8*)&QpA[quad * 8];
    bf16x8 qa1 = *(const bf16x8*)&QpA[32 + quad * 8];
    const bf16* QpB = QpA + 64 * 64;
    bf16x8 qb0 = *(const bf16x8*)&QpB[quad * 8];
    bf16x8 qb1 = *(const bf16x8*)&QpB[32 + quad * 8];

    bf16x8 ones;
#pragma unroll
    for (int i = 0; i < 8; ++i) ones[i] = (bf16)1.0f;
    const f32x4 fz = {0.f, 0.f, 0.f, 0.f};   // hoisted zero C operand

    f32x4 oA[4] = {}, oB[4] = {}, lA = {}, lB = {};

    int qrA = i0 + rg * 16 + l;
    const unsigned* seqA = pseq + (size_t)b * 131072 + (size_t)qrA * 64;
    const unsigned* spA = psp + (size_t)par * 131072 + (size_t)qrA * 64;
    const unsigned* seqB = seqA + 64 * 64;   // +64 q-rows
    const unsigned* spB = spA + 64 * 64;
    const bf16* Kbase = Kg + (size_t)bh * 2048 * 64;
    const bf16* Vbase = Vt + (size_t)bh * 64 * 2048;
    bf16* Pw = P + rg * 1152 + l * 72;
    const bf16* Pr = P + rg * 1152;

    int jlo = jc * 512;
    for (int jj = 0; jj < 8; ++jj) {
        int j0 = jlo + jj * 64;
        uint2 mseqA = *(const uint2*)&seqA[j0 >> 5];
        uint2 mspA = *(const uint2*)&spA[j0 >> 5];
        uint2 mseqB = *(const uint2*)&seqB[j0 >> 5];
        uint2 mspB = *(const uint2*)&spB[j0 >> 5];
        unsigned wA0 = mseqA.x & mspA.x, wA1 = mseqA.y & mspA.y;
        unsigned wB0 = mseqB.x & mspB.x, wB1 = mseqB.y & mspB.y;

        __syncthreads();
        stage_async(KT, Kbase + (size_t)j0 * 64, 64, t);
        stage_async(VT, Vbase + j0, 2048, t);
        __syncthreads();                     // drains vmcnt(0): staged tiles ready

        // S^T = K·Q^T for both q-subtiles; K frags loaded once, used twice
        f32x4 sA[4], sB[4];
        __builtin_amdgcn_s_setprio(1);
#pragma unroll
        for (int nc = 0; nc < 4; ++nc) {
            bf16x8 k0f = frag(KT, nc * 16 + l, quad);
            bf16x8 k1f = frag(KT, nc * 16 + l, 4 + quad);
            sA[nc] = MFMA(k0f, qa0, fz);
            sA[nc] = MFMA(k1f, qa1, sA[nc]);
            sB[nc] = MFMA(k0f, qb0, fz);
            sB[nc] = MFMA(k1f, qb1, sB[nc]);
        }
        __builtin_amdgcn_s_setprio(0);

        // fixed-max softmax A: p = bit ? exp2(s) : 0 (Q pre-scaled by log2e)
#pragma unroll
        for (int nc = 0; nc < 4; ++nc) {
            unsigned w = (nc < 2) ? wA0 : wA1;
            int bbase = (nc & 1) * 16 + quad * 4;
            bf16x4 pv;
#pragma unroll
            for (int r = 0; r < 4; ++r) {
                float e = __builtin_amdgcn_exp2f(sA[nc][r]);
                pv[r] = (bf16)(((w >> (bbase + r)) & 1u) ? e : 0.f);
            }
            *(bf16x4*)&Pw[nc * 16 + quad * 4] = pv;
        }
        bf16x8 paA0 = *(const bf16x8*)&Pr[l * 72 + quad * 8];
        bf16x8 paA1 = *(const bf16x8*)&Pr[l * 72 + 32 + quad * 8];

        // softmax B into the same P region: same-wave DS ops execute in order,
        // so the B writes cannot pass the A reads (proven pattern in R6).
#pragma unroll
        for (int nc = 0; nc < 4; ++nc) {
            unsigned w = (nc < 2) ? wB0 : wB1;
            int bbase = (nc & 1) * 16 + quad * 4;
            bf16x4 pv;
#pragma unroll
            for (int r = 0; r < 4; ++r) {
                float e = __builtin_amdgcn_exp2f(sB[nc][r]);
                pv[r] = (bf16)(((w >> (bbase + r)) & 1u) ? e : 0.f);
            }
            *(bf16x4*)&Pw[nc * 16 + quad * 4] = pv;
        }
        bf16x8 paB0 = *(const bf16x8*)&Pr[l * 72 + quad * 8];
        bf16x8 paB1 = *(const bf16x8*)&Pr[l * 72 + 32 + quad * 8];

        __builtin_amdgcn_s_setprio(1);
        lA = MFMA(paA0, ones, lA);
        lA = MFMA(paA1, ones, lA);
        lB = MFMA(paB0, ones, lB);
        lB = MFMA(paB1, ones, lB);
#pragma unroll
        for (int dc = 0; dc < 4; ++dc) {
            bf16x8 vb0 = frag(VT, dc * 16 + l, quad);
            bf16x8 vb1 = frag(VT, dc * 16 + l, 4 + quad);
            oA[dc] = MFMA(paA0, vb0, oA[dc]);
            oA[dc] = MFMA(paA1, vb1, oA[dc]);
            oB[dc] = MFMA(paB0, vb0, oB[dc]);
            oB[dc] = MFMA(paB1, vb1, oB[dc]);
        }
        __builtin_amdgcn_s_setprio(0);
    }

    int itA = itp * 2;
    size_t pbA = ((size_t)((bh * 32 + itA) * 4 + jc)) * 4096;
    size_t pbB = pbA + 4 * 4096;             // it = itA+1
#pragma unroll
    for (int dc = 0; dc < 4; ++dc)
#pragma unroll
        for (int r = 0; r < 4; ++r) {
            Opart[pbA + (size_t)(rg * 16 + quad * 4 + r) * 64 + dc * 16 + l] = oA[dc][r];
            Opart[pbB + (size_t)(rg * 16 + quad * 4 + r) * 64 + dc * 16 + l] = oB[dc][r];
        }
    if (l == 0) {
#pragma unroll
        for (int r = 0; r < 4; ++r) {
            Lpart[((bh * 32 + itA) * 4 + jc) * 64 + rg * 16 + quad * 4 + r] = lA[r];
            Lpart[((bh * 32 + itA + 1) * 4 + jc) * 64 + rg * 16 + quad * 4 + r] = lB[r];
        }
    }
}

// ---------------- combine partials -> normalized split-bf16 O (R6) ----------------
__global__ __launch_bounds__(256) void attn_combine(
    const float* __restrict__ Opart, const float* __restrict__ Lpart,
    bf16* __restrict__ Oh, bf16* __restrict__ Ol)
{
    int blk = blockIdx.x;
    int bh = blk >> 5, it = blk & 31;
    int t = threadIdx.x;
    int row = t >> 2, dseg = (t & 3) << 4;

    float acc[16] = {};
    float lsum = 0.f;
#pragma unroll
    for (int jc = 0; jc < 4; ++jc) {
        const float* Op = Opart + ((size_t)(blk * 4 + jc)) * 4096 + (size_t)row * 64 + dseg;
#pragma unroll
        for (int u = 0; u < 4; ++u) {
            float4 v = *(const float4*)&Op[u * 4];
            acc[u * 4 + 0] += v.x; acc[u * 4 + 1] += v.y;
            acc[u * 4 + 2] += v.z; acc[u * 4 + 3] += v.w;
        }
        lsum += Lpart[(blk * 4 + jc) * 64 + row];
    }
    float inv = 1.0f / lsum;
    int b = bh >> 3, h = bh & 7, tok = it * 64 + row;
    size_t base = ((size_t)b * 2048 + tok) * 512 + h * 64 + dseg;
    bf16x8 oh0, oh1, ol0, ol1;
#pragma unroll
    for (int u = 0; u < 8; ++u) {
        float v0 = acc[u] * inv, v1 = acc[8 + u] * inv;
        bf16 h0 = (bf16)v0, h1 = (bf16)v1;
        oh0[u] = h0; ol0[u] = (bf16)(v0 - (float)h0);
        oh1[u] = h1; ol1[u] = (bf16)(v1 - (float)h1);
    }
    *(bf16x8*)&Oh[base] = oh0;
    *(bf16x8*)&Oh[base + 8] = oh1;
    *(bf16x8*)&Ol[base] = ol0;
    *(bf16x8*)&Ol[base + 8] = ol1;
}

// ---------------- output projection, LDS-staged split-bf16 (R7 async) ----------------
__global__ __launch_bounds__(256) void gemm_out(
    const bf16* __restrict__ Ah, const bf16* __restrict__ Al,
    const bf16* __restrict__ Wh, const bf16* __restrict__ Wl,
    float* __restrict__ C)
{
    __shared__ bf16 AhT[4096], AlT[4096], WhT[4096], WlT[4096];
    int bid = blockIdx.x;
    int m0b = bid & 63, n0 = bid >> 6;
    int t = threadIdx.x, wave = t >> 6, lane = t & 63, l = lane & 15, quad = lane >> 4;
    int m0 = m0b * 64 + wave * 16;
    int nb = n0 * 64;
    f32x4 acc[4] = {};
    for (int k0 = 0; k0 < 512; k0 += 64) {
        __syncthreads();
        stage_async(AhT, Ah + (size_t)m0b * 64 * 512 + k0, 512, t);
        stage_async(AlT, Al + (size_t)m0b * 64 * 512 + k0, 512, t);
        stage_async(WhT, Wh + (size_t)nb * 512 + k0, 512, t);
        stage_async(WlT, Wl + (size_t)nb * 512 + k0, 512, t);
        __syncthreads();
        bf16x8 ah0 = frag(AhT, wave * 16 + l, quad);
        bf16x8 ah1 = frag(AhT, wave * 16 + l, 4 + quad);
        bf16x8 al0 = frag(AlT, wave * 16 + l, quad);
        bf16x8 al1 = frag(AlT, wave * 16 + l, 4 + quad);
#pragma unroll
        for (int nc = 0; nc < 4; ++nc) {
            bf16x8 bh0 = frag(WhT, nc * 16 + l, quad);
            bf16x8 bh1 = frag(WhT, nc * 16 + l, 4 + quad);
            bf16x8 bl0 = frag(WlT, nc * 16 + l, quad);
            bf16x8 bl1 = frag(WlT, nc * 16 + l, 4 + quad);
            acc[nc] = MFMA(ah0, bh0, acc[nc]);
            acc[nc] = MFMA(ah1, bh1, acc[nc]);
            acc[nc] = MFMA(ah0, bl0, acc[nc]);
            acc[nc] = MFMA(ah1, bl1, acc[nc]);
            acc[nc] = MFMA(al0, bh0, acc[nc]);
            acc[nc] = MFMA(al1, bh1, acc[nc]);
        }
    }
#pragma unroll
    for (int nc = 0; nc < 4; ++nc)
#pragma unroll
        for (int r = 0; r < 4; ++r)
            C[(size_t)(m0 + quad * 4 + r) * 512 + nb + nc * 16 + l] = acc[nc][r];
}

extern "C" void kernel_launch(void* const* d_in, const int* in_sizes, int n_in,
                              void* d_out, int out_size, void* d_ws, size_t ws_size,
                              hipStream_t stream) {
    const float* x = (const float*)d_in[0];
    const float* Wq = (const float*)d_in[1];
    const float* Wk = (const float*)d_in[2];
    const float* Wv = (const float*)d_in[3];
    const float* Wo = (const float*)d_in[4];
    const int* seqm = (const int*)d_in[5];
    const int* spm = (const int*)d_in[6];
    float* out = (float*)d_out;

    const size_t E = 2097152;            // 2*2048*512
    bf16* xb = (bf16*)d_ws;
    bf16* Wb = xb + E;
    bf16* Woh = Wb + 786432;
    bf16* Wol = Woh + 262144;
    bf16* Qg = Wol + 262144;
    bf16* Kg = Qg + E;
    bf16* Vtg = Kg + E;                  // [bh][64][2048]
    bf16* Ohb = Vtg + E;
    bf16* Olb = Ohb + E;
    unsigned* pseq = (unsigned*)(Olb + E);
    unsigned* psp = pseq + 262144;
    float* Opart = (float*)(psp + 262144);       // 2048 x 4096 fp32 = 32 MB
    float* Lpart = Opart + (size_t)2048 * 4096;  // 0.5 MB

    hipLaunchKernelGGL(prep, dim3(3584), dim3(256), 0, stream,
                       seqm, spm, x, Wq, Wk, Wv, Wo, pseq, psp, xb, Wb, Woh, Wol);
    hipLaunchKernelGGL(gemm_qkv, dim3(768), dim3(256), 0, stream, xb, Wb, Qg, Kg, Vtg);
    hipLaunchKernelGGL(attn_kernel, dim3(1024), dim3(256), 0, stream,
                       Qg, Kg, Vtg, pseq, psp, Opart, Lpart);
    hipLaunchKernelGGL(attn_combine, dim3(512), dim3(256), 0, stream, Opart, Lpart, Ohb, Olb);
    hipLaunchKernelGGL(gemm_out, dim3(512), dim3(256), 0, stream, Ohb, Olb, Woh, Wol, out);
}

// Round 2
// 178.670 us; speedup vs baseline: 1.1363x; 1.1363x over previous
//
#include <hip/hip_runtime.h>
#include <math.h>

typedef __bf16 bf16;
typedef __bf16 bf16x4 __attribute__((ext_vector_type(4)));
typedef __bf16 bf16x8 __attribute__((ext_vector_type(8)));
typedef float f32x4 __attribute__((ext_vector_type(4)));

#define MFMA(a, b, c) __builtin_amdgcn_mfma_f32_16x16x32_bf16(a, b, c, 0, 0, 0)
#define LOG2E 1.44269504088896340736f

// XOR-swizzled 64x64 bf16 tile (8 KB): elem (row, chunk8) at row*64 + ((ch^(row&7))*8).
// Staged via global_load_lds width=16 — linear LDS dest (wave-uniform base + lane*16),
// inverse-swizzled global source (rule #21: XOR involution -> frag() reads unchanged).
// Removes the VGPR round trip + staging VALU. Harness-verified correct in R1.
__device__ __forceinline__ void stage_async(bf16* __restrict__ T, const bf16* __restrict__ src,
                                            int rs, int t) {
#pragma unroll
    for (int i = 0; i < 2; ++i) {
        int u = i * 256 + t;                 // 16B chunk index in [0,512)
        int row = u >> 3, ch = u & 7;
        const bf16* g = src + (size_t)row * rs + ((ch ^ (row & 7)) << 3);
        bf16* lp = T + (size_t)(i * 256 + (t & 192)) * 8;   // wave-uniform base; HW adds lane*16
        __builtin_amdgcn_global_load_lds((__attribute__((address_space(1))) void*)g,
                                         (__attribute__((address_space(3))) void*)lp,
                                         16, 0, 0);
    }
}
__device__ __forceinline__ bf16x8 frag(const bf16* __restrict__ T, int row, int ch) {
    return *(const bf16x8*)&T[row * 64 + ((ch ^ (row & 7)) << 3)];
}

// ---------------- fused preprocessing (R8: vectorized mask packing) ----------------
__global__ __launch_bounds__(256) void prep(
    const int* __restrict__ seqm, const int* __restrict__ spm,
    const float* __restrict__ x,
    const float* __restrict__ Wq, const float* __restrict__ Wk,
    const float* __restrict__ Wv, const float* __restrict__ Wo,
    unsigned* __restrict__ pseq, unsigned* __restrict__ psp,
    bf16* __restrict__ xb, bf16* __restrict__ Wb,
    bf16* __restrict__ Woh, bf16* __restrict__ Wol)
{
    int bid = blockIdx.x, t = threadIdx.x;
    if (bid < 2048) {
        // one wave per 2048-col mask row; lane packs its own 32 columns (no ballots)
        int wave = t >> 6, lane = t & 63;
        int row = bid * 4 + wave;
        const int* src = (row < 4096) ? (seqm + (size_t)row * 2048)
                                      : (spm + (size_t)(row - 4096) * 2048);
        unsigned* dst = (row < 4096) ? (pseq + (size_t)row * 64)
                                     : (psp + (size_t)(row - 4096) * 64);
        const int4* s4 = (const int4*)src;
        unsigned bits = 0;
#pragma unroll
        for (int c = 0; c < 8; ++c) {
            int4 v = s4[lane * 8 + c];
            bits |= (v.x != 0 ? 1u : 0u) << (c * 4);
            bits |= (v.y != 0 ? 1u : 0u) << (c * 4 + 1);
            bits |= (v.z != 0 ? 1u : 0u) << (c * 4 + 2);
            bits |= (v.w != 0 ? 1u : 0u) << (c * 4 + 3);
        }
        dst[lane] = bits;
    } else if (bid < 3072) {
        int i = ((bid - 2048) * 256 + t) * 8;
        float4 a = *(const float4*)&x[i];
        float4 c = *(const float4*)&x[i + 4];
        float v[8] = {a.x, a.y, a.z, a.w, c.x, c.y, c.z, c.w};
        bf16x8 o;
#pragma unroll
        for (int u = 0; u < 8; ++u) o[u] = (bf16)v[u];
        *(bf16x8*)&xb[i] = o;
    } else {
        int zb = bid - 3072;
        int z = zb >> 7;
        int i = ((zb & 127) * 256 + t) * 8;
        const float* src = (z == 0) ? Wq : (z == 1) ? Wk : (z == 2) ? Wv : Wo;
        float4 a = *(const float4*)&src[i];
        float4 c = *(const float4*)&src[i + 4];
        float v[8] = {a.x, a.y, a.z, a.w, c.x, c.y, c.z, c.w};
        if (z < 3) {
            bf16x8 o;
#pragma unroll
            for (int u = 0; u < 8; ++u) o[u] = (bf16)v[u];
            *(bf16x8*)&Wb[(size_t)z * 262144 + i] = o;
        } else {
            bf16x8 oh, ol;
#pragma unroll
            for (int u = 0; u < 8; ++u) {
                bf16 hi = (bf16)v[u];
                oh[u] = hi;
                ol[u] = (bf16)(v[u] - (float)hi);
            }
            *(bf16x8*)&Woh[i] = oh;
            *(bf16x8*)&Wol[i] = ol;
        }
    }
}

// ---------------- fused QKV projection, 64x128 tiles ----------------
// grid 768 = m0b(64, XCD-sticky) x np(4) x z(3). Async LDS staging (R7, verified).
__global__ __launch_bounds__(256) void gemm_qkv(
    const bf16* __restrict__ A, const bf16* __restrict__ Wb,
    bf16* __restrict__ Qg, bf16* __restrict__ Kg, bf16* __restrict__ Vt)
{
    __shared__ bf16 AT[4096], WT0[4096], WT1[4096];
    __shared__ bf16 Lt[64 * 72];
    int bid = blockIdx.x;
    int m0b = bid & 63;
    int rest = bid >> 6;
    int np = rest & 3, z = rest >> 2;
    const bf16* W = Wb + (size_t)z * 262144;
    float scale = (z == 0) ? (0.125f * LOG2E) : 1.0f;

    int t = threadIdx.x, wave = t >> 6, lane = t & 63, l = lane & 15, quad = lane >> 4;
    int m0 = m0b * 64 + wave * 16;
    int nb = np * 128;
    f32x4 acc[8] = {};
    for (int k0 = 0; k0 < 512; k0 += 64) {
        __syncthreads();
        stage_async(AT, A + (size_t)m0b * 64 * 512 + k0, 512, t);
        stage_async(WT0, W + (size_t)nb * 512 + k0, 512, t);
        stage_async(WT1, W + (size_t)(nb + 64) * 512 + k0, 512, t);
        __syncthreads();
        bf16x8 a0 = frag(AT, wave * 16 + l, quad);
        bf16x8 a1 = frag(AT, wave * 16 + l, 4 + quad);
#pragma unroll
        for (int nc = 0; nc < 4; ++nc) {
            bf16x8 b0 = frag(WT0, nc * 16 + l, quad);
            bf16x8 b1 = frag(WT0, nc * 16 + l, 4 + quad);
            acc[nc] = MFMA(a0, b0, acc[nc]);
            acc[nc] = MFMA(a1, b1, acc[nc]);
        }
#pragma unroll
        for (int nc = 0; nc < 4; ++nc) {
            bf16x8 b0 = frag(WT1, nc * 16 + l, quad);
            bf16x8 b1 = frag(WT1, nc * 16 + l, 4 + quad);
            acc[4 + nc] = MFMA(a0, b0, acc[4 + nc]);
            acc[4 + nc] = MFMA(a1, b1, acc[4 + nc]);
        }
    }
    if (z < 2) {
        bf16* out = (z == 0) ? Qg : Kg;
#pragma unroll
        for (int nc = 0; nc < 8; ++nc) {
#pragma unroll
            for (int r = 0; r < 4; ++r) {
                int m = m0 + quad * 4 + r;
                int feat = nb + nc * 16 + l;
                int b = m >> 11, tok = m & 2047, h = feat >> 6, d = feat & 63;
                out[(((size_t)(b * 8 + h)) * 2048 + tok) * 64 + d] = (bf16)(acc[nc][r] * scale);
            }
        }
    } else {
#pragma unroll
        for (int hh = 0; hh < 2; ++hh) {
            __syncthreads();
#pragma unroll
            for (int nc = 0; nc < 4; ++nc)
#pragma unroll
                for (int r = 0; r < 4; ++r)
                    Lt[(nc * 16 + l) * 72 + wave * 16 + quad * 4 + r] = (bf16)acc[hh * 4 + nc][r];
            __syncthreads();
            int d = t >> 2, seg = t & 3;
            int tok0 = m0b * 64;
            int b = tok0 >> 11, h = np * 2 + hh;
            bf16x8 o0, o1;
#pragma unroll
            for (int i = 0; i < 8; ++i) { o0[i] = Lt[d * 72 + seg * 16 + i]; o1[i] = Lt[d * 72 + seg * 16 + 8 + i]; }
            size_t base = ((size_t)(b * 8 + h) * 64 + d) * 2048 + (tok0 & 2047) + seg * 16;
            *(bf16x8*)&Vt[base] = o0;
            *(bf16x8*)&Vt[base + 8] = o1;
        }
    }
}

// ---------------- flash attention (R8): R6 geometry + async staging + setprio --------
// grid 2048 = jc(2b) | it(5b) | bh(4b); 4 waves; LDS 25.6 KB -> 6 blocks/CU.
// R7 post-mortem: 128-row blocks doubled per-block Opart writes -> L2 thrash
// (WRITE 2x, FETCH +32MB). Reverted to 64-row blocks (WRITE=33MB clean).
__global__ __launch_bounds__(256) void attn_kernel(
    const bf16* __restrict__ Qg, const bf16* __restrict__ Kg, const bf16* __restrict__ Vt,
    const unsigned* __restrict__ pseq, const unsigned* __restrict__ psp,
    float* __restrict__ Opart, float* __restrict__ Lpart)
{
    __shared__ bf16 KT[4096], VT[4096];
    __shared__ bf16 P[4 * 16 * 72];
    int bid = blockIdx.x;
    int bh = bid & 15;                       // XCD = bid%8 -> K/V L2-resident
    int it = (bid >> 4) & 31;
    int jc = bid >> 9;
    int i0 = it * 64;
    int b = bh >> 3, par = bh & 1;
    int t = threadIdx.x, rg = t >> 6, lane = t & 63, l = lane & 15, quad = lane >> 4;

    const bf16* Qp = Qg + ((size_t)bh * 2048 + i0 + rg * 16 + l) * 64;
    bf16x8 qf0 = *(const bf16x8*)&Qp[quad * 8];
    bf16x8 qf1 = *(const bf16x8*)&Qp[32 + quad * 8];

    bf16x8 ones;
#pragma unroll
    for (int i = 0; i < 8; ++i) ones[i] = (bf16)1.0f;
    const f32x4 fz = {0.f, 0.f, 0.f, 0.f};   // hoisted zero C operand

    f32x4 o_acc[4] = {}, l_acc = {};

    int qrow = i0 + rg * 16 + l;
    const unsigned* seqp = pseq + (size_t)b * 131072 + (size_t)qrow * 64;
    const unsigned* sppp = psp + (size_t)par * 131072 + (size_t)qrow * 64;
    const bf16* Kbase = Kg + (size_t)bh * 2048 * 64;
    const bf16* Vbase = Vt + (size_t)bh * 64 * 2048;
    bf16* Pw = P + rg * 1152 + l * 72;
    const bf16* Pr = P + rg * 1152;

    int jlo = jc * 512, jhi = jlo + 512;
    for (int j0 = jlo; j0 < jhi; j0 += 64) {
        uint2 mseq = *(const uint2*)&seqp[j0 >> 5];
        uint2 msp = *(const uint2*)&sppp[j0 >> 5];
        unsigned w0 = mseq.x & msp.x, w1 = mseq.y & msp.y;

        __syncthreads();
        stage_async(KT, Kbase + (size_t)j0 * 64, 64, t);
        stage_async(VT, Vbase + j0, 2048, t);
        __syncthreads();                     // drains vmcnt(0): staged tiles ready

        // S^T = K·Q^T (col = query lane), seeded from fz (no per-tile acc zeroing)
        f32x4 s[4];
        __builtin_amdgcn_s_setprio(1);
#pragma unroll
        for (int nc = 0; nc < 4; ++nc) {
            bf16x8 k0f = frag(KT, nc * 16 + l, quad);
            bf16x8 k1f = frag(KT, nc * 16 + l, 4 + quad);
            s[nc] = MFMA(k0f, qf0, fz);
            s[nc] = MFMA(k1f, qf1, s[nc]);
        }
        __builtin_amdgcn_s_setprio(0);

        // fixed-max softmax: p = bit ? exp2(s) : 0 (Q pre-scaled by log2e)
#pragma unroll
        for (int nc = 0; nc < 4; ++nc) {
            unsigned w = (nc < 2) ? w0 : w1;
            int bbase = (nc & 1) * 16 + quad * 4;
            bf16x4 pv;
#pragma unroll
            for (int r = 0; r < 4; ++r) {
                float e = __builtin_amdgcn_exp2f(s[nc][r]);
                pv[r] = (bf16)(((w >> (bbase + r)) & 1u) ? e : 0.f);
            }
            *(bf16x4*)&Pw[nc * 16 + quad * 4] = pv;
        }

        bf16x8 pa0 = *(const bf16x8*)&Pr[l * 72 + quad * 8];
        bf16x8 pa1 = *(const bf16x8*)&Pr[l * 72 + 32 + quad * 8];
        __builtin_amdgcn_s_setprio(1);
        l_acc = MFMA(pa0, ones, l_acc);
        l_acc = MFMA(pa1, ones, l_acc);
#pragma unroll
        for (int dc = 0; dc < 4; ++dc) {
            bf16x8 vb0 = frag(VT, dc * 16 + l, quad);
            bf16x8 vb1 = frag(VT, dc * 16 + l, 4 + quad);
            o_acc[dc] = MFMA(pa0, vb0, o_acc[dc]);
            o_acc[dc] = MFMA(pa1, vb1, o_acc[dc]);
        }
        __builtin_amdgcn_s_setprio(0);
    }

    size_t pb = ((size_t)((bh * 32 + it) * 4 + jc)) * 4096;
#pragma unroll
    for (int dc = 0; dc < 4; ++dc)
#pragma unroll
        for (int r = 0; r < 4; ++r)
            Opart[pb + (size_t)(rg * 16 + quad * 4 + r) * 64 + dc * 16 + l] = o_acc[dc][r];
    if (l == 0) {
#pragma unroll
        for (int r = 0; r < 4; ++r)
            Lpart[((bh * 32 + it) * 4 + jc) * 64 + rg * 16 + quad * 4 + r] = l_acc[r];
    }
}

// ---------------- combine partials -> normalized split-bf16 O (R6) ----------------
__global__ __launch_bounds__(256) void attn_combine(
    const float* __restrict__ Opart, const float* __restrict__ Lpart,
    bf16* __restrict__ Oh, bf16* __restrict__ Ol)
{
    int blk = blockIdx.x;
    int bh = blk >> 5, it = blk & 31;
    int t = threadIdx.x;
    int row = t >> 2, dseg = (t & 3) << 4;

    float acc[16] = {};
    float lsum = 0.f;
#pragma unroll
    for (int jc = 0; jc < 4; ++jc) {
        const float* Op = Opart + ((size_t)(blk * 4 + jc)) * 4096 + (size_t)row * 64 + dseg;
#pragma unroll
        for (int u = 0; u < 4; ++u) {
            float4 v = *(const float4*)&Op[u * 4];
            acc[u * 4 + 0] += v.x; acc[u * 4 + 1] += v.y;
            acc[u * 4 + 2] += v.z; acc[u * 4 + 3] += v.w;
        }
        lsum += Lpart[(blk * 4 + jc) * 64 + row];
    }
    float inv = 1.0f / lsum;
    int b = bh >> 3, h = bh & 7, tok = it * 64 + row;
    size_t base = ((size_t)b * 2048 + tok) * 512 + h * 64 + dseg;
    bf16x8 oh0, oh1, ol0, ol1;
#pragma unroll
    for (int u = 0; u < 8; ++u) {
        float v0 = acc[u] * inv, v1 = acc[8 + u] * inv;
        bf16 h0 = (bf16)v0, h1 = (bf16)v1;
        oh0[u] = h0; ol0[u] = (bf16)(v0 - (float)h0);
        oh1[u] = h1; ol1[u] = (bf16)(v1 - (float)h1);
    }
    *(bf16x8*)&Oh[base] = oh0;
    *(bf16x8*)&Oh[base + 8] = oh1;
    *(bf16x8*)&Ol[base] = ol0;
    *(bf16x8*)&Ol[base + 8] = ol1;
}

// ---------------- output projection, LDS-staged split-bf16 (async) ----------------
__global__ __launch_bounds__(256) void gemm_out(
    const bf16* __restrict__ Ah, const bf16* __restrict__ Al,
    const bf16* __restrict__ Wh, const bf16* __restrict__ Wl,
    float* __restrict__ C)
{
    __shared__ bf16 AhT[4096], AlT[4096], WhT[4096], WlT[4096];
    int bid = blockIdx.x;
    int m0b = bid & 63, n0 = bid >> 6;
    int t = threadIdx.x, wave = t >> 6, lane = t & 63, l = lane & 15, quad = lane >> 4;
    int m0 = m0b * 64 + wave * 16;
    int nb = n0 * 64;
    f32x4 acc[4] = {};
    for (int k0 = 0; k0 < 512; k0 += 64) {
        __syncthreads();
        stage_async(AhT, Ah + (size_t)m0b * 64 * 512 + k0, 512, t);
        stage_async(AlT, Al + (size_t)m0b * 64 * 512 + k0, 512, t);
        stage_async(WhT, Wh + (size_t)nb * 512 + k0, 512, t);
        stage_async(WlT, Wl + (size_t)nb * 512 + k0, 512, t);
        __syncthreads();
        bf16x8 ah0 = frag(AhT, wave * 16 + l, quad);
        bf16x8 ah1 = frag(AhT, wave * 16 + l, 4 + quad);
        bf16x8 al0 = frag(AlT, wave * 16 + l, quad);
        bf16x8 al1 = frag(AlT, wave * 16 + l, 4 + quad);
#pragma unroll
        for (int nc = 0; nc < 4; ++nc) {
            bf16x8 bh0 = frag(WhT, nc * 16 + l, quad);
            bf16x8 bh1 = frag(WhT, nc * 16 + l, 4 + quad);
            bf16x8 bl0 = frag(WlT, nc * 16 + l, quad);
            bf16x8 bl1 = frag(WlT, nc * 16 + l, 4 + quad);
            acc[nc] = MFMA(ah0, bh0, acc[nc]);
            acc[nc] = MFMA(ah1, bh1, acc[nc]);
            acc[nc] = MFMA(ah0, bl0, acc[nc]);
            acc[nc] = MFMA(ah1, bl1, acc[nc]);
            acc[nc] = MFMA(al0, bh0, acc[nc]);
            acc[nc] = MFMA(al1, bh1, acc[nc]);
        }
    }
#pragma unroll
    for (int nc = 0; nc < 4; ++nc)
#pragma unroll
        for (int r = 0; r < 4; ++r)
            C[(size_t)(m0 + quad * 4 + r) * 512 + nb + nc * 16 + l] = acc[nc][r];
}

extern "C" void kernel_launch(void* const* d_in, const int* in_sizes, int n_in,
                              void* d_out, int out_size, void* d_ws, size_t ws_size,
                              hipStream_t stream) {
    const float* x = (const float*)d_in[0];
    const float* Wq = (const float*)d_in[1];
    const float* Wk = (const float*)d_in[2];
    const float* Wv = (const float*)d_in[3];
    const float* Wo = (const float*)d_in[4];
    const int* seqm = (const int*)d_in[5];
    const int* spm = (const int*)d_in[6];
    float* out = (float*)d_out;

    const size_t E = 2097152;            // 2*2048*512
    bf16* xb = (bf16*)d_ws;
    bf16* Wb = xb + E;
    bf16* Woh = Wb + 786432;
    bf16* Wol = Woh + 262144;
    bf16* Qg = Wol + 262144;
    bf16* Kg = Qg + E;
    bf16* Vtg = Kg + E;                  // [bh][64][2048]
    bf16* Ohb = Vtg + E;
    bf16* Olb = Ohb + E;
    unsigned* pseq = (unsigned*)(Olb + E);
    unsigned* psp = pseq + 262144;
    float* Opart = (float*)(psp + 262144);       // 2048 x 4096 fp32 = 32 MB
    float* Lpart = Opart + (size_t)2048 * 4096;  // 0.5 MB

    hipLaunchKernelGGL(prep, dim3(3584), dim3(256), 0, stream,
                       seqm, spm, x, Wq, Wk, Wv, Wo, pseq, psp, xb, Wb, Woh, Wol);
    hipLaunchKernelGGL(gemm_qkv, dim3(768), dim3(256), 0, stream, xb, Wb, Qg, Kg, Vtg);
    hipLaunchKernelGGL(attn_kernel, dim3(2048), dim3(256), 0, stream,
                       Qg, Kg, Vtg, pseq, psp, Opart, Lpart);
    hipLaunchKernelGGL(attn_combine, dim3(512), dim3(256), 0, stream, Opart, Lpart, Ohb, Olb);
    hipLaunchKernelGGL(gemm_out, dim3(512), dim3(256), 0, stream, Ohb, Olb, Woh, Wol, out);
}

// Round 3
// 178.474 us; speedup vs baseline: 1.1376x; 1.0011x over previous
//
#include <hip/hip_runtime.h>
#include <math.h>

typedef __bf16 bf16;
typedef __bf16 bf16x4 __attribute__((ext_vector_type(4)));
typedef __bf16 bf16x8 __attribute__((ext_vector_type(8)));
typedef float f32x4 __attribute__((ext_vector_type(4)));

#define MFMA(a, b, c) __builtin_amdgcn_mfma_f32_16x16x32_bf16(a, b, c, 0, 0, 0)
#define LOG2E 1.44269504088896340736f

// XOR-swizzled 64x64 bf16 tile (8 KB): elem (row, chunk8) at row*64 + ((ch^(row&7))*8).
// Staged via global_load_lds width=16 — linear LDS dest (wave-uniform base + lane*16),
// inverse-swizzled global source (rule #21: XOR involution -> frag() reads unchanged).
__device__ __forceinline__ void stage_async(bf16* __restrict__ T, const bf16* __restrict__ src,
                                            int rs, int t) {
#pragma unroll
    for (int i = 0; i < 2; ++i) {
        int u = i * 256 + t;                 // 16B chunk index in [0,512)
        int row = u >> 3, ch = u & 7;
        const bf16* g = src + (size_t)row * rs + ((ch ^ (row & 7)) << 3);
        bf16* lp = T + (size_t)(i * 256 + (t & 192)) * 8;   // wave-uniform base; HW adds lane*16
        __builtin_amdgcn_global_load_lds((__attribute__((address_space(1))) void*)g,
                                         (__attribute__((address_space(3))) void*)lp,
                                         16, 0, 0);
    }
}
__device__ __forceinline__ bf16x8 frag(const bf16* __restrict__ T, int row, int ch) {
    return *(const bf16x8*)&T[row * 64 + ((ch ^ (row & 7)) << 3)];
}
// P tile [16 rows][64 cols] with 16B-slot XOR swizzle: elem (l,k) at
// l*64 + ((k>>3 ^ (l&7))<<3) + (k&7). Writes (4-elem, k%8 in {0,4}) and reads
// (8-elem, k%8==0) stay within one slot; banks spread 8-way, <=2-way conflict (free).
__device__ __forceinline__ int pidx(int l, int k) {
    return l * 64 + ((((k >> 3) ^ (l & 7))) << 3) + (k & 7);
}

// ---------------- fused preprocessing (R8: vectorized mask packing) ----------------
__global__ __launch_bounds__(256) void prep(
    const int* __restrict__ seqm, const int* __restrict__ spm,
    const float* __restrict__ x,
    const float* __restrict__ Wq, const float* __restrict__ Wk,
    const float* __restrict__ Wv, const float* __restrict__ Wo,
    unsigned* __restrict__ pseq, unsigned* __restrict__ psp,
    bf16* __restrict__ xb, bf16* __restrict__ Wb,
    bf16* __restrict__ Woh, bf16* __restrict__ Wol)
{
    int bid = blockIdx.x, t = threadIdx.x;
    if (bid < 2048) {
        int wave = t >> 6, lane = t & 63;
        int row = bid * 4 + wave;
        const int* src = (row < 4096) ? (seqm + (size_t)row * 2048)
                                      : (spm + (size_t)(row - 4096) * 2048);
        unsigned* dst = (row < 4096) ? (pseq + (size_t)row * 64)
                                     : (psp + (size_t)(row - 4096) * 64);
        const int4* s4 = (const int4*)src;
        unsigned bits = 0;
#pragma unroll
        for (int c = 0; c < 8; ++c) {
            int4 v = s4[lane * 8 + c];
            bits |= (v.x != 0 ? 1u : 0u) << (c * 4);
            bits |= (v.y != 0 ? 1u : 0u) << (c * 4 + 1);
            bits |= (v.z != 0 ? 1u : 0u) << (c * 4 + 2);
            bits |= (v.w != 0 ? 1u : 0u) << (c * 4 + 3);
        }
        dst[lane] = bits;
    } else if (bid < 3072) {
        int i = ((bid - 2048) * 256 + t) * 8;
        float4 a = *(const float4*)&x[i];
        float4 c = *(const float4*)&x[i + 4];
        float v[8] = {a.x, a.y, a.z, a.w, c.x, c.y, c.z, c.w};
        bf16x8 o;
#pragma unroll
        for (int u = 0; u < 8; ++u) o[u] = (bf16)v[u];
        *(bf16x8*)&xb[i] = o;
    } else {
        int zb = bid - 3072;
        int z = zb >> 7;
        int i = ((zb & 127) * 256 + t) * 8;
        const float* src = (z == 0) ? Wq : (z == 1) ? Wk : (z == 2) ? Wv : Wo;
        float4 a = *(const float4*)&src[i];
        float4 c = *(const float4*)&src[i + 4];
        float v[8] = {a.x, a.y, a.z, a.w, c.x, c.y, c.z, c.w};
        if (z < 3) {
            bf16x8 o;
#pragma unroll
            for (int u = 0; u < 8; ++u) o[u] = (bf16)v[u];
            *(bf16x8*)&Wb[(size_t)z * 262144 + i] = o;
        } else {
            bf16x8 oh, ol;
#pragma unroll
            for (int u = 0; u < 8; ++u) {
                bf16 hi = (bf16)v[u];
                oh[u] = hi;
                ol[u] = (bf16)(v[u] - (float)hi);
            }
            *(bf16x8*)&Woh[i] = oh;
            *(bf16x8*)&Wol[i] = ol;
        }
    }
}

// ---------------- fused QKV projection, 64x128 tiles ----------------
__global__ __launch_bounds__(256) void gemm_qkv(
    const bf16* __restrict__ A, const bf16* __restrict__ Wb,
    bf16* __restrict__ Qg, bf16* __restrict__ Kg, bf16* __restrict__ Vt)
{
    __shared__ bf16 AT[4096], WT0[4096], WT1[4096];
    __shared__ bf16 Lt[64 * 72];
    int bid = blockIdx.x;
    int m0b = bid & 63;
    int rest = bid >> 6;
    int np = rest & 3, z = rest >> 2;
    const bf16* W = Wb + (size_t)z * 262144;
    float scale = (z == 0) ? (0.125f * LOG2E) : 1.0f;

    int t = threadIdx.x, wave = t >> 6, lane = t & 63, l = lane & 15, quad = lane >> 4;
    int m0 = m0b * 64 + wave * 16;
    int nb = np * 128;
    f32x4 acc[8] = {};
    for (int k0 = 0; k0 < 512; k0 += 64) {
        __syncthreads();
        stage_async(AT, A + (size_t)m0b * 64 * 512 + k0, 512, t);
        stage_async(WT0, W + (size_t)nb * 512 + k0, 512, t);
        stage_async(WT1, W + (size_t)(nb + 64) * 512 + k0, 512, t);
        __syncthreads();
        bf16x8 a0 = frag(AT, wave * 16 + l, quad);
        bf16x8 a1 = frag(AT, wave * 16 + l, 4 + quad);
#pragma unroll
        for (int nc = 0; nc < 4; ++nc) {
            bf16x8 b0 = frag(WT0, nc * 16 + l, quad);
            bf16x8 b1 = frag(WT0, nc * 16 + l, 4 + quad);
            acc[nc] = MFMA(a0, b0, acc[nc]);
            acc[nc] = MFMA(a1, b1, acc[nc]);
        }
#pragma unroll
        for (int nc = 0; nc < 4; ++nc) {
            bf16x8 b0 = frag(WT1, nc * 16 + l, quad);
            bf16x8 b1 = frag(WT1, nc * 16 + l, 4 + quad);
            acc[4 + nc] = MFMA(a0, b0, acc[4 + nc]);
            acc[4 + nc] = MFMA(a1, b1, acc[4 + nc]);
        }
    }
    if (z < 2) {
        bf16* out = (z == 0) ? Qg : Kg;
#pragma unroll
        for (int nc = 0; nc < 8; ++nc) {
#pragma unroll
            for (int r = 0; r < 4; ++r) {
                int m = m0 + quad * 4 + r;
                int feat = nb + nc * 16 + l;
                int b = m >> 11, tok = m & 2047, h = feat >> 6, d = feat & 63;
                out[(((size_t)(b * 8 + h)) * 2048 + tok) * 64 + d] = (bf16)(acc[nc][r] * scale);
            }
        }
    } else {
#pragma unroll
        for (int hh = 0; hh < 2; ++hh) {
            __syncthreads();
#pragma unroll
            for (int nc = 0; nc < 4; ++nc)
#pragma unroll
                for (int r = 0; r < 4; ++r)
                    Lt[(nc * 16 + l) * 72 + wave * 16 + quad * 4 + r] = (bf16)acc[hh * 4 + nc][r];
            __syncthreads();
            int d = t >> 2, seg = t & 3;
            int tok0 = m0b * 64;
            int b = tok0 >> 11, h = np * 2 + hh;
            bf16x8 o0, o1;
#pragma unroll
            for (int i = 0; i < 8; ++i) { o0[i] = Lt[d * 72 + seg * 16 + i]; o1[i] = Lt[d * 72 + seg * 16 + 8 + i]; }
            size_t base = ((size_t)(b * 8 + h) * 64 + d) * 2048 + (tok0 & 2047) + seg * 16;
            *(bf16x8*)&Vt[base] = o0;
            *(bf16x8*)&Vt[base + 8] = o1;
        }
    }
}

// ---------------- flash attention (R9): 2-phase double-buffered K/V, jc=2 ----------
// grid 1024 = jc(1b) | it(5b) | bh(4b); 4 waves; LDS 40960 B -> exactly 4 blocks/CU
// (single full-residency round). Per tile: issue next-tile global_load_lds BEFORE
// compute; one barrier/tile whose vmcnt(0) drain lands after ~400cyc of MFMA+softmax
// (load latency hidden). Per-block Opart write stays 16 KB (R7 thrash avoided);
// total Opart traffic halves vs jc=4.
__global__ __launch_bounds__(256) void attn_kernel(
    const bf16* __restrict__ Qg, const bf16* __restrict__ Kg, const bf16* __restrict__ Vt,
    const unsigned* __restrict__ pseq, const unsigned* __restrict__ psp,
    float* __restrict__ Opart, float* __restrict__ Lpart)
{
    __shared__ bf16 KT[2][4096], VT[2][4096];
    __shared__ bf16 P[4][1024];
    int bid = blockIdx.x;
    int bh = bid & 15;                       // XCD = bid%8 -> K/V L2-resident
    int it = (bid >> 4) & 31;
    int jc = bid >> 9;                       // 0..1
    int i0 = it * 64;
    int b = bh >> 3, par = bh & 1;
    int t = threadIdx.x, rg = t >> 6, lane = t & 63, l = lane & 15, quad = lane >> 4;

    const bf16* Qp = Qg + ((size_t)bh * 2048 + i0 + rg * 16 + l) * 64;
    bf16x8 qf0 = *(const bf16x8*)&Qp[quad * 8];
    bf16x8 qf1 = *(const bf16x8*)&Qp[32 + quad * 8];

    bf16x8 ones;
#pragma unroll
    for (int i = 0; i < 8; ++i) ones[i] = (bf16)1.0f;
    const f32x4 fz = {0.f, 0.f, 0.f, 0.f};

    f32x4 o_acc[4] = {}, l_acc = {};

    int qrow = i0 + rg * 16 + l;
    const unsigned* seqp = pseq + (size_t)b * 131072 + (size_t)qrow * 64;
    const unsigned* sppp = psp + (size_t)par * 131072 + (size_t)qrow * 64;
    const bf16* Kbase = Kg + (size_t)bh * 2048 * 64;
    const bf16* Vbase = Vt + (size_t)bh * 64 * 2048;
    bf16* Pb = P[rg];

    const int NT = 16;
    int jlo = jc * 1024;

    // prologue: stage tile 0 into buffer 0
    stage_async(KT[0], Kbase + (size_t)jlo * 64, 64, t);
    stage_async(VT[0], Vbase + jlo, 2048, t);
    __syncthreads();

    for (int jj = 0; jj < NT; ++jj) {
        int cur = jj & 1;
        int j0 = jlo + jj * 64;
        uint2 mseq = *(const uint2*)&seqp[j0 >> 5];
        uint2 msp = *(const uint2*)&sppp[j0 >> 5];
        unsigned w0 = mseq.x & msp.x, w1 = mseq.y & msp.y;

        // issue next-tile loads first; latency hides under this tile's compute
        if (jj + 1 < NT) {
            stage_async(KT[cur ^ 1], Kbase + (size_t)(j0 + 64) * 64, 64, t);
            stage_async(VT[cur ^ 1], Vbase + (j0 + 64), 2048, t);
        }

        // S^T = K·Q^T (col = query lane), seeded from fz
        f32x4 s[4];
        __builtin_amdgcn_s_setprio(1);
#pragma unroll
        for (int nc = 0; nc < 4; ++nc) {
            bf16x8 k0f = frag(KT[cur], nc * 16 + l, quad);
            bf16x8 k1f = frag(KT[cur], nc * 16 + l, 4 + quad);
            s[nc] = MFMA(k0f, qf0, fz);
            s[nc] = MFMA(k1f, qf1, s[nc]);
        }
        __builtin_amdgcn_s_setprio(0);

        // fixed-max softmax: p = bit ? exp2(s) : 0 (Q pre-scaled by log2e)
#pragma unroll
        for (int nc = 0; nc < 4; ++nc) {
            unsigned w = (nc < 2) ? w0 : w1;
            int bbase = (nc & 1) * 16 + quad * 4;
            bf16x4 pv;
#pragma unroll
            for (int r = 0; r < 4; ++r) {
                float e = __builtin_amdgcn_exp2f(s[nc][r]);
                pv[r] = (bf16)(((w >> (bbase + r)) & 1u) ? e : 0.f);
            }
            *(bf16x4*)&Pb[pidx(l, nc * 16 + quad * 4)] = pv;
        }

        bf16x8 pa0 = *(const bf16x8*)&Pb[pidx(l, quad * 8)];
        bf16x8 pa1 = *(const bf16x8*)&Pb[pidx(l, 32 + quad * 8)];
        __builtin_amdgcn_s_setprio(1);
        l_acc = MFMA(pa0, ones, l_acc);
        l_acc = MFMA(pa1, ones, l_acc);
#pragma unroll
        for (int dc = 0; dc < 4; ++dc) {
            bf16x8 vb0 = frag(VT[cur], dc * 16 + l, quad);
            bf16x8 vb1 = frag(VT[cur], dc * 16 + l, 4 + quad);
            o_acc[dc] = MFMA(pa0, vb0, o_acc[dc]);
            o_acc[dc] = MFMA(pa1, vb1, o_acc[dc]);
        }
        __builtin_amdgcn_s_setprio(0);
        __syncthreads();   // drains next-tile vmcnt + all LDS; one barrier per tile
    }

    size_t pb = ((size_t)((bh * 32 + it) * 2 + jc)) * 4096;
#pragma unroll
    for (int dc = 0; dc < 4; ++dc)
#pragma unroll
        for (int r = 0; r < 4; ++r)
            Opart[pb + (size_t)(rg * 16 + quad * 4 + r) * 64 + dc * 16 + l] = o_acc[dc][r];
    if (l == 0) {
#pragma unroll
        for (int r = 0; r < 4; ++r)
            Lpart[((bh * 32 + it) * 2 + jc) * 64 + rg * 16 + quad * 4 + r] = l_acc[r];
    }
}

// ---------------- combine partials -> normalized split-bf16 O (jc=2) ----------------
__global__ __launch_bounds__(256) void attn_combine(
    const float* __restrict__ Opart, const float* __restrict__ Lpart,
    bf16* __restrict__ Oh, bf16* __restrict__ Ol)
{
    int blk = blockIdx.x;
    int bh = blk >> 5, it = blk & 31;
    int t = threadIdx.x;
    int row = t >> 2, dseg = (t & 3) << 4;

    float acc[16] = {};
    float lsum = 0.f;
#pragma unroll
    for (int jc = 0; jc < 2; ++jc) {
        const float* Op = Opart + ((size_t)(blk * 2 + jc)) * 4096 + (size_t)row * 64 + dseg;
#pragma unroll
        for (int u = 0; u < 4; ++u) {
            float4 v = *(const float4*)&Op[u * 4];
            acc[u * 4 + 0] += v.x; acc[u * 4 + 1] += v.y;
            acc[u * 4 + 2] += v.z; acc[u * 4 + 3] += v.w;
        }
        lsum += Lpart[(blk * 2 + jc) * 64 + row];
    }
    float inv = 1.0f / lsum;
    int b = bh >> 3, h = bh & 7, tok = it * 64 + row;
    size_t base = ((size_t)b * 2048 + tok) * 512 + h * 64 + dseg;
    bf16x8 oh0, oh1, ol0, ol1;
#pragma unroll
    for (int u = 0; u < 8; ++u) {
        float v0 = acc[u] * inv, v1 = acc[8 + u] * inv;
        bf16 h0 = (bf16)v0, h1 = (bf16)v1;
        oh0[u] = h0; ol0[u] = (bf16)(v0 - (float)h0);
        oh1[u] = h1; ol1[u] = (bf16)(v1 - (float)h1);
    }
    *(bf16x8*)&Oh[base] = oh0;
    *(bf16x8*)&Oh[base + 8] = oh1;
    *(bf16x8*)&Ol[base] = ol0;
    *(bf16x8*)&Ol[base + 8] = ol1;
}

// ---------------- output projection, LDS-staged split-bf16 (async) ----------------
__global__ __launch_bounds__(256) void gemm_out(
    const bf16* __restrict__ Ah, const bf16* __restrict__ Al,
    const bf16* __restrict__ Wh, const bf16* __restrict__ Wl,
    float* __restrict__ C)
{
    __shared__ bf16 AhT[4096], AlT[4096], WhT[4096], WlT[4096];
    int bid = blockIdx.x;
    int m0b = bid & 63, n0 = bid >> 6;
    int t = threadIdx.x, wave = t >> 6, lane = t & 63, l = lane & 15, quad = lane >> 4;
    int m0 = m0b * 64 + wave * 16;
    int nb = n0 * 64;
    f32x4 acc[4] = {};
    for (int k0 = 0; k0 < 512; k0 += 64) {
        __syncthreads();
        stage_async(AhT, Ah + (size_t)m0b * 64 * 512 + k0, 512, t);
        stage_async(AlT, Al + (size_t)m0b * 64 * 512 + k0, 512, t);
        stage_async(WhT, Wh + (size_t)nb * 512 + k0, 512, t);
        stage_async(WlT, Wl + (size_t)nb * 512 + k0, 512, t);
        __syncthreads();
        bf16x8 ah0 = frag(AhT, wave * 16 + l, quad);
        bf16x8 ah1 = frag(AhT, wave * 16 + l, 4 + quad);
        bf16x8 al0 = frag(AlT, wave * 16 + l, quad);
        bf16x8 al1 = frag(AlT, wave * 16 + l, 4 + quad);
#pragma unroll
        for (int nc = 0; nc < 4; ++nc) {
            bf16x8 bh0 = frag(WhT, nc * 16 + l, quad);
            bf16x8 bh1 = frag(WhT, nc * 16 + l, 4 + quad);
            bf16x8 bl0 = frag(WlT, nc * 16 + l, quad);
            bf16x8 bl1 = frag(WlT, nc * 16 + l, 4 + quad);
            acc[nc] = MFMA(ah0, bh0, acc[nc]);
            acc[nc] = MFMA(ah1, bh1, acc[nc]);
            acc[nc] = MFMA(ah0, bl0, acc[nc]);
            acc[nc] = MFMA(ah1, bl1, acc[nc]);
            acc[nc] = MFMA(al0, bh0, acc[nc]);
            acc[nc] = MFMA(al1, bh1, acc[nc]);
        }
    }
#pragma unroll
    for (int nc = 0; nc < 4; ++nc)
#pragma unroll
        for (int r = 0; r < 4; ++r)
            C[(size_t)(m0 + quad * 4 + r) * 512 + nb + nc * 16 + l] = acc[nc][r];
}

extern "C" void kernel_launch(void* const* d_in, const int* in_sizes, int n_in,
                              void* d_out, int out_size, void* d_ws, size_t ws_size,
                              hipStream_t stream) {
    const float* x = (const float*)d_in[0];
    const float* Wq = (const float*)d_in[1];
    const float* Wk = (const float*)d_in[2];
    const float* Wv = (const float*)d_in[3];
    const float* Wo = (const float*)d_in[4];
    const int* seqm = (const int*)d_in[5];
    const int* spm = (const int*)d_in[6];
    float* out = (float*)d_out;

    const size_t E = 2097152;            // 2*2048*512
    bf16* xb = (bf16*)d_ws;
    bf16* Wb = xb + E;
    bf16* Woh = Wb + 786432;
    bf16* Wol = Woh + 262144;
    bf16* Qg = Wol + 262144;
    bf16* Kg = Qg + E;
    bf16* Vtg = Kg + E;                  // [bh][64][2048]
    bf16* Ohb = Vtg + E;
    bf16* Olb = Ohb + E;
    unsigned* pseq = (unsigned*)(Olb + E);
    unsigned* psp = pseq + 262144;
    float* Opart = (float*)(psp + 262144);       // 1024 x 4096 fp32 = 16 MB
    float* Lpart = Opart + (size_t)1024 * 4096;  // 0.25 MB

    hipLaunchKernelGGL(prep, dim3(3584), dim3(256), 0, stream,
                       seqm, spm, x, Wq, Wk, Wv, Wo, pseq, psp, xb, Wb, Woh, Wol);
    hipLaunchKernelGGL(gemm_qkv, dim3(768), dim3(256), 0, stream, xb, Wb, Qg, Kg, Vtg);
    hipLaunchKernelGGL(attn_kernel, dim3(1024), dim3(256), 0, stream,
                       Qg, Kg, Vtg, pseq, psp, Opart, Lpart);
    hipLaunchKernelGGL(attn_combine, dim3(512), dim3(256), 0, stream, Opart, Lpart, Ohb, Olb);
    hipLaunchKernelGGL(gemm_out, dim3(512), dim3(256), 0, stream, Ohb, Olb, Woh, Wol, out);
}

// Round 5
// 177.429 us; speedup vs baseline: 1.1443x; 1.0059x over previous
//
#include <hip/hip_runtime.h>
#include <math.h>

typedef __bf16 bf16;
typedef __bf16 bf16x4 __attribute__((ext_vector_type(4)));
typedef __bf16 bf16x8 __attribute__((ext_vector_type(8)));
typedef float f32x4 __attribute__((ext_vector_type(4)));

#define MFMA(a, b, c) __builtin_amdgcn_mfma_f32_16x16x32_bf16(a, b, c, 0, 0, 0)
#define LOG2E 1.44269504088896340736f

// XOR-swizzled 64x64 bf16 tile (8 KB): elem (row, chunk8) at row*64 + ((ch^(row&7))*8).
// Staged via global_load_lds width=16 — linear LDS dest (wave-uniform base + lane*16),
// inverse-swizzled global source (rule #21: XOR involution -> frag() reads unchanged).
__device__ __forceinline__ void stage_async(bf16* __restrict__ T, const bf16* __restrict__ src,
                                            int rs, int t) {
#pragma unroll
    for (int i = 0; i < 2; ++i) {
        int u = i * 256 + t;                 // 16B chunk index in [0,512)
        int row = u >> 3, ch = u & 7;
        const bf16* g = src + (size_t)row * rs + ((ch ^ (row & 7)) << 3);
        bf16* lp = T + (size_t)(i * 256 + (t & 192)) * 8;   // wave-uniform base; HW adds lane*16
        __builtin_amdgcn_global_load_lds((__attribute__((address_space(1))) void*)g,
                                         (__attribute__((address_space(3))) void*)lp,
                                         16, 0, 0);
    }
}
__device__ __forceinline__ bf16x8 frag(const bf16* __restrict__ T, int row, int ch) {
    return *(const bf16x8*)&T[row * 64 + ((ch ^ (row & 7)) << 3)];
}

// ---------------- fused preprocessing (R8: vectorized mask packing) ----------------
__global__ __launch_bounds__(256) void prep(
    const int* __restrict__ seqm, const int* __restrict__ spm,
    const float* __restrict__ x,
    const float* __restrict__ Wq, const float* __restrict__ Wk,
    const float* __restrict__ Wv, const float* __restrict__ Wo,
    unsigned* __restrict__ pseq, unsigned* __restrict__ psp,
    bf16* __restrict__ xb, bf16* __restrict__ Wb,
    bf16* __restrict__ Woh, bf16* __restrict__ Wol)
{
    int bid = blockIdx.x, t = threadIdx.x;
    if (bid < 2048) {
        int wave = t >> 6, lane = t & 63;
        int row = bid * 4 + wave;
        const int* src = (row < 4096) ? (seqm + (size_t)row * 2048)
                                      : (spm + (size_t)(row - 4096) * 2048);
        unsigned* dst = (row < 4096) ? (pseq + (size_t)row * 64)
                                     : (psp + (size_t)(row - 4096) * 64);
        const int4* s4 = (const int4*)src;
        unsigned bits = 0;
#pragma unroll
        for (int c = 0; c < 8; ++c) {
            int4 v = s4[lane * 8 + c];
            bits |= (v.x != 0 ? 1u : 0u) << (c * 4);
            bits |= (v.y != 0 ? 1u : 0u) << (c * 4 + 1);
            bits |= (v.z != 0 ? 1u : 0u) << (c * 4 + 2);
            bits |= (v.w != 0 ? 1u : 0u) << (c * 4 + 3);
        }
        dst[lane] = bits;
    } else if (bid < 3072) {
        int i = ((bid - 2048) * 256 + t) * 8;
        float4 a = *(const float4*)&x[i];
        float4 c = *(const float4*)&x[i + 4];
        float v[8] = {a.x, a.y, a.z, a.w, c.x, c.y, c.z, c.w};
        bf16x8 o;
#pragma unroll
        for (int u = 0; u < 8; ++u) o[u] = (bf16)v[u];
        *(bf16x8*)&xb[i] = o;
    } else {
        int zb = bid - 3072;
        int z = zb >> 7;
        int i = ((zb & 127) * 256 + t) * 8;
        const float* src = (z == 0) ? Wq : (z == 1) ? Wk : (z == 2) ? Wv : Wo;
        float4 a = *(const float4*)&src[i];
        float4 c = *(const float4*)&src[i + 4];
        float v[8] = {a.x, a.y, a.z, a.w, c.x, c.y, c.z, c.w};
        if (z < 3) {
            bf16x8 o;
#pragma unroll
            for (int u = 0; u < 8; ++u) o[u] = (bf16)v[u];
            *(bf16x8*)&Wb[(size_t)z * 262144 + i] = o;
        } else {
            bf16x8 oh, ol;
#pragma unroll
            for (int u = 0; u < 8; ++u) {
                bf16 hi = (bf16)v[u];
                oh[u] = hi;
                ol[u] = (bf16)(v[u] - (float)hi);
            }
            *(bf16x8*)&Woh[i] = oh;
            *(bf16x8*)&Wol[i] = ol;
        }
    }
}

// ---------------- fused QKV projection (R12: single-barrier dbuf staging) ----------
// grid 768 = m0b(64) x np(4) x z(3); LDS 48KB (2 sets x 3 tiles; Lt aliased on set0,
// used only post-loop) -> 3 blocks/CU, grid exactly resident. One barrier per k-step;
// the vmcnt(0) drain of stage(k+1) lands one full k-step of MFMA after issue (T3
// 2-phase recipe). Reads of set X all precede the barrier that precedes X's re-stage.
__global__ __launch_bounds__(256) void gemm_qkv(
    const bf16* __restrict__ A, const bf16* __restrict__ Wb,
    bf16* __restrict__ Qg, bf16* __restrict__ Kg, bf16* __restrict__ Vt)
{
    __shared__ bf16 SM[24576];           // set s at SM + s*12288 (tiles +0,+4096,+8192)
    bf16* Lt = SM;                       // epilogue scratch, post-loop only
    int bid = blockIdx.x;
    int m0b = bid & 63;
    int rest = bid >> 6;
    int np = rest & 3, z = rest >> 2;
    const bf16* W = Wb + (size_t)z * 262144;
    float scale = (z == 0) ? (0.125f * LOG2E) : 1.0f;

    int t = threadIdx.x, wave = t >> 6, lane = t & 63, l = lane & 15, quad = lane >> 4;
    int m0 = m0b * 64 + wave * 16;
    int nb = np * 128;
    const bf16* Abase = A + (size_t)m0b * 64 * 512;
    const bf16* W0base = W + (size_t)nb * 512;
    const bf16* W1base = W + (size_t)(nb + 64) * 512;

    stage_async(SM, Abase, 512, t);
    stage_async(SM + 4096, W0base, 512, t);
    stage_async(SM + 8192, W1base, 512, t);

    f32x4 acc[8] = {};
    for (int ks = 0; ks < 8; ++ks) {
        bf16* set = SM + (ks & 1) * 12288;
        __syncthreads();                 // drains stage(ks) vmcnt + prior set reads
        if (ks < 7) {
            int k0 = (ks + 1) * 64;
            bf16* nset = SM + ((ks + 1) & 1) * 12288;
            stage_async(nset, Abase + k0, 512, t);
            stage_async(nset + 4096, W0base + k0, 512, t);
            stage_async(nset + 8192, W1base + k0, 512, t);
        }
        bf16x8 a0 = frag(set, wave * 16 + l, quad);
        bf16x8 a1 = frag(set, wave * 16 + l, 4 + quad);
#pragma unroll
        for (int nc = 0; nc < 4; ++nc) {
            bf16x8 b0 = frag(set + 4096, nc * 16 + l, quad);
            bf16x8 b1 = frag(set + 4096, nc * 16 + l, 4 + quad);
            acc[nc] = MFMA(a0, b0, acc[nc]);
            acc[nc] = MFMA(a1, b1, acc[nc]);
        }
#pragma unroll
        for (int nc = 0; nc < 4; ++nc) {
            bf16x8 b0 = frag(set + 8192, nc * 16 + l, quad);
            bf16x8 b1 = frag(set + 8192, nc * 16 + l, 4 + quad);
            acc[4 + nc] = MFMA(a0, b0, acc[4 + nc]);
            acc[4 + nc] = MFMA(a1, b1, acc[4 + nc]);
        }
    }
    if (z < 2) {
        bf16* out = (z == 0) ? Qg : Kg;
#pragma unroll
        for (int nc = 0; nc < 8; ++nc) {
#pragma unroll
            for (int r = 0; r < 4; ++r) {
                int m = m0 + quad * 4 + r;
                int feat = nb + nc * 16 + l;
                int b = m >> 11, tok = m & 2047, h = feat >> 6, d = feat & 63;
                out[(((size_t)(b * 8 + h)) * 2048 + tok) * 64 + d] = (bf16)(acc[nc][r] * scale);
            }
        }
    } else {
#pragma unroll
        for (int hh = 0; hh < 2; ++hh) {
            __syncthreads();
#pragma unroll
            for (int nc = 0; nc < 4; ++nc)
#pragma unroll
                for (int r = 0; r < 4; ++r)
                    Lt[(nc * 16 + l) * 72 + wave * 16 + quad * 4 + r] = (bf16)acc[hh * 4 + nc][r];
            __syncthreads();
            int d = t >> 2, seg = t & 3;
            int tok0 = m0b * 64;
            int b = tok0 >> 11, h = np * 2 + hh;
            bf16x8 o0, o1;
#pragma unroll
            for (int i = 0; i < 8; ++i) { o0[i] = Lt[d * 72 + seg * 16 + i]; o1[i] = Lt[d * 72 + seg * 16 + 8 + i]; }
            size_t base = ((size_t)(b * 8 + h) * 64 + d) * 2048 + (tok0 & 2047) + seg * 16;
            *(bf16x8*)&Vt[base] = o0;
            *(bf16x8*)&Vt[base + 8] = o1;
        }
    }
}

// ---------------- flash attention (R2-exact: best measured 43.5us) ----------------
// grid 2048 = jc(2b) | it(5b) | bh(4b); 4 waves; LDS 25.6 KB -> 6 blocks/CU.
__global__ __launch_bounds__(256) void attn_kernel(
    const bf16* __restrict__ Qg, const bf16* __restrict__ Kg, const bf16* __restrict__ Vt,
    const unsigned* __restrict__ pseq, const unsigned* __restrict__ psp,
    float* __restrict__ Opart, float* __restrict__ Lpart)
{
    __shared__ bf16 KT[4096], VT[4096];
    __shared__ bf16 P[4 * 16 * 72];
    int bid = blockIdx.x;
    int bh = bid & 15;                       // XCD = bid%8 -> K/V L2-resident
    int it = (bid >> 4) & 31;
    int jc = bid >> 9;
    int i0 = it * 64;
    int b = bh >> 3, par = bh & 1;
    int t = threadIdx.x, rg = t >> 6, lane = t & 63, l = lane & 15, quad = lane >> 4;

    const bf16* Qp = Qg + ((size_t)bh * 2048 + i0 + rg * 16 + l) * 64;
    bf16x8 qf0 = *(const bf16x8*)&Qp[quad * 8];
    bf16x8 qf1 = *(const bf16x8*)&Qp[32 + quad * 8];

    bf16x8 ones;
#pragma unroll
    for (int i = 0; i < 8; ++i) ones[i] = (bf16)1.0f;
    const f32x4 fz = {0.f, 0.f, 0.f, 0.f};   // hoisted zero C operand

    f32x4 o_acc[4] = {}, l_acc = {};

    int qrow = i0 + rg * 16 + l;
    const unsigned* seqp = pseq + (size_t)b * 131072 + (size_t)qrow * 64;
    const unsigned* sppp = psp + (size_t)par * 131072 + (size_t)qrow * 64;
    const bf16* Kbase = Kg + (size_t)bh * 2048 * 64;
    const bf16* Vbase = Vt + (size_t)bh * 64 * 2048;
    bf16* Pw = P + rg * 1152 + l * 72;
    const bf16* Pr = P + rg * 1152;

    int jlo = jc * 512, jhi = jlo + 512;
    for (int j0 = jlo; j0 < jhi; j0 += 64) {
        uint2 mseq = *(const uint2*)&seqp[j0 >> 5];
        uint2 msp = *(const uint2*)&sppp[j0 >> 5];
        unsigned w0 = mseq.x & msp.x, w1 = mseq.y & msp.y;

        __syncthreads();
        stage_async(KT, Kbase + (size_t)j0 * 64, 64, t);
        stage_async(VT, Vbase + j0, 2048, t);
        __syncthreads();                     // drains vmcnt(0): staged tiles ready

        // S^T = K·Q^T (col = query lane), seeded from fz (no per-tile acc zeroing)
        f32x4 s[4];
        __builtin_amdgcn_s_setprio(1);
#pragma unroll
        for (int nc = 0; nc < 4; ++nc) {
            bf16x8 k0f = frag(KT, nc * 16 + l, quad);
            bf16x8 k1f = frag(KT, nc * 16 + l, 4 + quad);
            s[nc] = MFMA(k0f, qf0, fz);
            s[nc] = MFMA(k1f, qf1, s[nc]);
        }
        __builtin_amdgcn_s_setprio(0);

        // fixed-max softmax: p = bit ? exp2(s) : 0 (Q pre-scaled by log2e)
#pragma unroll
        for (int nc = 0; nc < 4; ++nc) {
            unsigned w = (nc < 2) ? w0 : w1;
            int bbase = (nc & 1) * 16 + quad * 4;
            bf16x4 pv;
#pragma unroll
            for (int r = 0; r < 4; ++r) {
                float e = __builtin_amdgcn_exp2f(s[nc][r]);
                pv[r] = (bf16)(((w >> (bbase + r)) & 1u) ? e : 0.f);
            }
            *(bf16x4*)&Pw[nc * 16 + quad * 4] = pv;
        }

        bf16x8 pa0 = *(const bf16x8*)&Pr[l * 72 + quad * 8];
        bf16x8 pa1 = *(const bf16x8*)&Pr[l * 72 + 32 + quad * 8];
        __builtin_amdgcn_s_setprio(1);
        l_acc = MFMA(pa0, ones, l_acc);
        l_acc = MFMA(pa1, ones, l_acc);
#pragma unroll
        for (int dc = 0; dc < 4; ++dc) {
            bf16x8 vb0 = frag(VT, dc * 16 + l, quad);
            bf16x8 vb1 = frag(VT, dc * 16 + l, 4 + quad);
            o_acc[dc] = MFMA(pa0, vb0, o_acc[dc]);
            o_acc[dc] = MFMA(pa1, vb1, o_acc[dc]);
        }
        __builtin_amdgcn_s_setprio(0);
    }

    size_t pb = ((size_t)((bh * 32 + it) * 4 + jc)) * 4096;
#pragma unroll
    for (int dc = 0; dc < 4; ++dc)
#pragma unroll
        for (int r = 0; r < 4; ++r)
            Opart[pb + (size_t)(rg * 16 + quad * 4 + r) * 64 + dc * 16 + l] = o_acc[dc][r];
    if (l == 0) {
#pragma unroll
        for (int r = 0; r < 4; ++r)
            Lpart[((bh * 32 + it) * 4 + jc) * 64 + rg * 16 + quad * 4 + r] = l_acc[r];
    }
}

// ---------------- combine partials -> normalized split-bf16 O (R2-exact) -----------
__global__ __launch_bounds__(256) void attn_combine(
    const float* __restrict__ Opart, const float* __restrict__ Lpart,
    bf16* __restrict__ Oh, bf16* __restrict__ Ol)
{
    int blk = blockIdx.x;
    int bh = blk >> 5, it = blk & 31;
    int t = threadIdx.x;
    int row = t >> 2, dseg = (t & 3) << 4;

    float acc[16] = {};
    float lsum = 0.f;
#pragma unroll
    for (int jc = 0; jc < 4; ++jc) {
        const float* Op = Opart + ((size_t)(blk * 4 + jc)) * 4096 + (size_t)row * 64 + dseg;
#pragma unroll
        for (int u = 0; u < 4; ++u) {
            float4 v = *(const float4*)&Op[u * 4];
            acc[u * 4 + 0] += v.x; acc[u * 4 + 1] += v.y;
            acc[u * 4 + 2] += v.z; acc[u * 4 + 3] += v.w;
        }
        lsum += Lpart[(blk * 4 + jc) * 64 + row];
    }
    float inv = 1.0f / lsum;
    int b = bh >> 3, h = bh & 7, tok = it * 64 + row;
    size_t base = ((size_t)b * 2048 + tok) * 512 + h * 64 + dseg;
    bf16x8 oh0, oh1, ol0, ol1;
#pragma unroll
    for (int u = 0; u < 8; ++u) {
        float v0 = acc[u] * inv, v1 = acc[8 + u] * inv;
        bf16 h0 = (bf16)v0, h1 = (bf16)v1;
        oh0[u] = h0; ol0[u] = (bf16)(v0 - (float)h0);
        oh1[u] = h1; ol1[u] = (bf16)(v1 - (float)h1);
    }
    *(bf16x8*)&Oh[base] = oh0;
    *(bf16x8*)&Oh[base + 8] = oh1;
    *(bf16x8*)&Ol[base] = ol0;
    *(bf16x8*)&Ol[base + 8] = ol1;
}

// ---------------- output projection, LDS-staged split-bf16 (R3-exact) --------------
__global__ __launch_bounds__(256) void gemm_out(
    const bf16* __restrict__ Ah, const bf16* __restrict__ Al,
    const bf16* __restrict__ Wh, const bf16* __restrict__ Wl,
    float* __restrict__ C)
{
    __shared__ bf16 AhT[4096], AlT[4096], WhT[4096], WlT[4096];
    int bid = blockIdx.x;
    int m0b = bid & 63, n0 = bid >> 6;
    int t = threadIdx.x, wave = t >> 6, lane = t & 63, l = lane & 15, quad = lane >> 4;
    int m0 = m0b * 64 + wave * 16;
    int nb = n0 * 64;
    f32x4 acc[4] = {};
    for (int k0 = 0; k0 < 512; k0 += 64) {
        __syncthreads();
        stage_async(AhT, Ah + (size_t)m0b * 64 * 512 + k0, 512, t);
        stage_async(AlT, Al + (size_t)m0b * 64 * 512 + k0, 512, t);
        stage_async(WhT, Wh + (size_t)nb * 512 + k0, 512, t);
        stage_async(WlT, Wl + (size_t)nb * 512 + k0, 512, t);
        __syncthreads();
        bf16x8 ah0 = frag(AhT, wave * 16 + l, quad);
        bf16x8 ah1 = frag(AhT, wave * 16 + l, 4 + quad);
        bf16x8 al0 = frag(AlT, wave * 16 + l, quad);
        bf16x8 al1 = frag(AlT, wave * 16 + l, 4 + quad);
#pragma unroll
        for (int nc = 0; nc < 4; ++nc) {
            bf16x8 bh0 = frag(WhT, nc * 16 + l, quad);
            bf16x8 bh1 = frag(WhT, nc * 16 + l, 4 + quad);
            bf16x8 bl0 = frag(WlT, nc * 16 + l, quad);
            bf16x8 bl1 = frag(WlT, nc * 16 + l, 4 + quad);
            acc[nc] = MFMA(ah0, bh0, acc[nc]);
            acc[nc] = MFMA(ah1, bh1, acc[nc]);
            acc[nc] = MFMA(ah0, bl0, acc[nc]);
            acc[nc] = MFMA(ah1, bl1, acc[nc]);
            acc[nc] = MFMA(al0, bh0, acc[nc]);
            acc[nc] = MFMA(al1, bh1, acc[nc]);
        }
    }
#pragma unroll
    for (int nc = 0; nc < 4; ++nc)
#pragma unroll
        for (int r = 0; r < 4; ++r)
            C[(size_t)(m0 + quad * 4 + r) * 512 + nb + nc * 16 + l] = acc[nc][r];
}

extern "C" void kernel_launch(void* const* d_in, const int* in_sizes, int n_in,
                              void* d_out, int out_size, void* d_ws, size_t ws_size,
                              hipStream_t stream) {
    const float* x = (const float*)d_in[0];
    const float* Wq = (const float*)d_in[1];
    const float* Wk = (const float*)d_in[2];
    const float* Wv = (const float*)d_in[3];
    const float* Wo = (const float*)d_in[4];
    const int* seqm = (const int*)d_in[5];
    const int* spm = (const int*)d_in[6];
    float* out = (float*)d_out;

    const size_t E = 2097152;            // 2*2048*512
    bf16* xb = (bf16*)d_ws;
    bf16* Wb = xb + E;
    bf16* Woh = Wb + 786432;
    bf16* Wol = Woh + 262144;
    bf16* Qg = Wol + 262144;
    bf16* Kg = Qg + E;
    bf16* Vtg = Kg + E;                  // [bh][64][2048]
    bf16* Ohb = Vtg + E;
    bf16* Olb = Ohb + E;
    unsigned* pseq = (unsigned*)(Olb + E);
    unsigned* psp = pseq + 262144;
    float* Opart = (float*)(psp + 262144);       // 2048 x 4096 fp32 = 32 MB
    float* Lpart = Opart + (size_t)2048 * 4096;  // 0.5 MB

    hipLaunchKernelGGL(prep, dim3(3584), dim3(256), 0, stream,
                       seqm, spm, x, Wq, Wk, Wv, Wo, pseq, psp, xb, Wb, Woh, Wol);
    hipLaunchKernelGGL(gemm_qkv, dim3(768), dim3(256), 0, stream, xb, Wb, Qg, Kg, Vtg);
    hipLaunchKernelGGL(attn_kernel, dim3(2048), dim3(256), 0, stream,
                       Qg, Kg, Vtg, pseq, psp, Opart, Lpart);
    hipLaunchKernelGGL(attn_combine, dim3(512), dim3(256), 0, stream, Opart, Lpart, Ohb, Olb);
    hipLaunchKernelGGL(gemm_out, dim3(512), dim3(256), 0, stream, Ohb, Olb, Woh, Wol, out);
}

// Round 6
// 175.228 us; speedup vs baseline: 1.1587x; 1.0126x over previous
//
#include <hip/hip_runtime.h>
#include <math.h>

typedef __bf16 bf16;
typedef __bf16 bf16x4 __attribute__((ext_vector_type(4)));
typedef __bf16 bf16x8 __attribute__((ext_vector_type(8)));
typedef float f32x4 __attribute__((ext_vector_type(4)));

#define MFMA(a, b, c) __builtin_amdgcn_mfma_f32_16x16x32_bf16(a, b, c, 0, 0, 0)
#define LOG2E 1.44269504088896340736f

// XOR-swizzled 64x64 bf16 tile (8 KB): elem (row, chunk8) at row*64 + ((ch^(row&7))*8).
// Staged via global_load_lds width=16 — linear LDS dest (wave-uniform base + lane*16),
// inverse-swizzled global source (rule #21: XOR involution -> frag() reads unchanged).
__device__ __forceinline__ void stage_async(bf16* __restrict__ T, const bf16* __restrict__ src,
                                            int rs, int t) {
#pragma unroll
    for (int i = 0; i < 2; ++i) {
        int u = i * 256 + t;                 // 16B chunk index in [0,512)
        int row = u >> 3, ch = u & 7;
        const bf16* g = src + (size_t)row * rs + ((ch ^ (row & 7)) << 3);
        bf16* lp = T + (size_t)(i * 256 + (t & 192)) * 8;   // wave-uniform base; HW adds lane*16
        __builtin_amdgcn_global_load_lds((__attribute__((address_space(1))) void*)g,
                                         (__attribute__((address_space(3))) void*)lp,
                                         16, 0, 0);
    }
}
__device__ __forceinline__ bf16x8 frag(const bf16* __restrict__ T, int row, int ch) {
    return *(const bf16x8*)&T[row * 64 + ((ch ^ (row & 7)) << 3)];
}
// P tile [16 rows][64 cols] with 16B-slot XOR swizzle; <=2-way conflicts (free).
__device__ __forceinline__ int pidx(int l, int k) {
    return l * 64 + ((((k >> 3) ^ (l & 7))) << 3) + (k & 7);
}

// ---------------- fused preprocessing (R8: vectorized mask packing) ----------------
__global__ __launch_bounds__(256) void prep(
    const int* __restrict__ seqm, const int* __restrict__ spm,
    const float* __restrict__ x,
    const float* __restrict__ Wq, const float* __restrict__ Wk,
    const float* __restrict__ Wv, const float* __restrict__ Wo,
    unsigned* __restrict__ pseq, unsigned* __restrict__ psp,
    bf16* __restrict__ xb, bf16* __restrict__ Wb,
    bf16* __restrict__ Woh, bf16* __restrict__ Wol)
{
    int bid = blockIdx.x, t = threadIdx.x;
    if (bid < 2048) {
        int wave = t >> 6, lane = t & 63;
        int row = bid * 4 + wave;
        const int* src = (row < 4096) ? (seqm + (size_t)row * 2048)
                                      : (spm + (size_t)(row - 4096) * 2048);
        unsigned* dst = (row < 4096) ? (pseq + (size_t)row * 64)
                                     : (psp + (size_t)(row - 4096) * 64);
        const int4* s4 = (const int4*)src;
        unsigned bits = 0;
#pragma unroll
        for (int c = 0; c < 8; ++c) {
            int4 v = s4[lane * 8 + c];
            bits |= (v.x != 0 ? 1u : 0u) << (c * 4);
            bits |= (v.y != 0 ? 1u : 0u) << (c * 4 + 1);
            bits |= (v.z != 0 ? 1u : 0u) << (c * 4 + 2);
            bits |= (v.w != 0 ? 1u : 0u) << (c * 4 + 3);
        }
        dst[lane] = bits;
    } else if (bid < 3072) {
        int i = ((bid - 2048) * 256 + t) * 8;
        float4 a = *(const float4*)&x[i];
        float4 c = *(const float4*)&x[i + 4];
        float v[8] = {a.x, a.y, a.z, a.w, c.x, c.y, c.z, c.w};
        bf16x8 o;
#pragma unroll
        for (int u = 0; u < 8; ++u) o[u] = (bf16)v[u];
        *(bf16x8*)&xb[i] = o;
    } else {
        int zb = bid - 3072;
        int z = zb >> 7;
        int i = ((zb & 127) * 256 + t) * 8;
        const float* src = (z == 0) ? Wq : (z == 1) ? Wk : (z == 2) ? Wv : Wo;
        float4 a = *(const float4*)&src[i];
        float4 c = *(const float4*)&src[i + 4];
        float v[8] = {a.x, a.y, a.z, a.w, c.x, c.y, c.z, c.w};
        if (z < 3) {
            bf16x8 o;
#pragma unroll
            for (int u = 0; u < 8; ++u) o[u] = (bf16)v[u];
            *(bf16x8*)&Wb[(size_t)z * 262144 + i] = o;
        } else {
            bf16x8 oh, ol;
#pragma unroll
            for (int u = 0; u < 8; ++u) {
                bf16 hi = (bf16)v[u];
                oh[u] = hi;
                ol[u] = (bf16)(v[u] - (float)hi);
            }
            *(bf16x8*)&Woh[i] = oh;
            *(bf16x8*)&Wol[i] = ol;
        }
    }
}

// ---------------- fused QKV projection (R5-proven: single-barrier dbuf) ------------
__global__ __launch_bounds__(256) void gemm_qkv(
    const bf16* __restrict__ A, const bf16* __restrict__ Wb,
    bf16* __restrict__ Qg, bf16* __restrict__ Kg, bf16* __restrict__ Vt)
{
    __shared__ bf16 SM[24576];           // set s at SM + s*12288 (tiles +0,+4096,+8192)
    bf16* Lt = SM;                       // epilogue scratch, post-loop only
    int bid = blockIdx.x;
    int m0b = bid & 63;
    int rest = bid >> 6;
    int np = rest & 3, z = rest >> 2;
    const bf16* W = Wb + (size_t)z * 262144;
    float scale = (z == 0) ? (0.125f * LOG2E) : 1.0f;

    int t = threadIdx.x, wave = t >> 6, lane = t & 63, l = lane & 15, quad = lane >> 4;
    int m0 = m0b * 64 + wave * 16;
    int nb = np * 128;
    const bf16* Abase = A + (size_t)m0b * 64 * 512;
    const bf16* W0base = W + (size_t)nb * 512;
    const bf16* W1base = W + (size_t)(nb + 64) * 512;

    stage_async(SM, Abase, 512, t);
    stage_async(SM + 4096, W0base, 512, t);
    stage_async(SM + 8192, W1base, 512, t);

    f32x4 acc[8] = {};
    for (int ks = 0; ks < 8; ++ks) {
        bf16* set = SM + (ks & 1) * 12288;
        __syncthreads();                 // drains stage(ks) vmcnt + prior set reads
        if (ks < 7) {
            int k0 = (ks + 1) * 64;
            bf16* nset = SM + ((ks + 1) & 1) * 12288;
            stage_async(nset, Abase + k0, 512, t);
            stage_async(nset + 4096, W0base + k0, 512, t);
            stage_async(nset + 8192, W1base + k0, 512, t);
        }
        bf16x8 a0 = frag(set, wave * 16 + l, quad);
        bf16x8 a1 = frag(set, wave * 16 + l, 4 + quad);
#pragma unroll
        for (int nc = 0; nc < 4; ++nc) {
            bf16x8 b0 = frag(set + 4096, nc * 16 + l, quad);
            bf16x8 b1 = frag(set + 4096, nc * 16 + l, 4 + quad);
            acc[nc] = MFMA(a0, b0, acc[nc]);
            acc[nc] = MFMA(a1, b1, acc[nc]);
        }
#pragma unroll
        for (int nc = 0; nc < 4; ++nc) {
            bf16x8 b0 = frag(set + 8192, nc * 16 + l, quad);
            bf16x8 b1 = frag(set + 8192, nc * 16 + l, 4 + quad);
            acc[4 + nc] = MFMA(a0, b0, acc[4 + nc]);
            acc[4 + nc] = MFMA(a1, b1, acc[4 + nc]);
        }
    }
    if (z < 2) {
        bf16* out = (z == 0) ? Qg : Kg;
#pragma unroll
        for (int nc = 0; nc < 8; ++nc) {
#pragma unroll
            for (int r = 0; r < 4; ++r) {
                int m = m0 + quad * 4 + r;
                int feat = nb + nc * 16 + l;
                int b = m >> 11, tok = m & 2047, h = feat >> 6, d = feat & 63;
                out[(((size_t)(b * 8 + h)) * 2048 + tok) * 64 + d] = (bf16)(acc[nc][r] * scale);
            }
        }
    } else {
#pragma unroll
        for (int hh = 0; hh < 2; ++hh) {
            __syncthreads();
#pragma unroll
            for (int nc = 0; nc < 4; ++nc)
#pragma unroll
                for (int r = 0; r < 4; ++r)
                    Lt[(nc * 16 + l) * 72 + wave * 16 + quad * 4 + r] = (bf16)acc[hh * 4 + nc][r];
            __syncthreads();
            int d = t >> 2, seg = t & 3;
            int tok0 = m0b * 64;
            int b = tok0 >> 11, h = np * 2 + hh;
            bf16x8 o0, o1;
#pragma unroll
            for (int i = 0; i < 8; ++i) { o0[i] = Lt[d * 72 + seg * 16 + i]; o1[i] = Lt[d * 72 + seg * 16 + 8 + i]; }
            size_t base = ((size_t)(b * 8 + h) * 64 + d) * 2048 + (tok0 & 2047) + seg * 16;
            *(bf16x8*)&Vt[base] = o0;
            *(bf16x8*)&Vt[base + 8] = o1;
        }
    }
}

// ---------------- flash attention (R6 = audited T15 cross-tile pipeline) -----------
// grid 1024 = jc(1b) | it(5b) | bh(4b); 4 waves; LDS 40KB -> 4 blocks/CU resident.
// PV(j-1) runs concurrently with QK(j)+softmax(j): V(j-1) pre-read to regs before its
// buffer is re-staged (2nd barrier protects cross-wave WAR); P fragments carried in
// regs across iterations. Single new element vs R5 (crash attribution probe).
__global__ __launch_bounds__(256, 4) void attn_kernel(
    const bf16* __restrict__ Qg, const bf16* __restrict__ Kg, const bf16* __restrict__ Vt,
    const unsigned* __restrict__ pseq, const unsigned* __restrict__ psp,
    float* __restrict__ Opart, float* __restrict__ Lpart)
{
    __shared__ bf16 KT[2][4096], VT[2][4096];
    __shared__ bf16 P[4][1024];
    int bid = blockIdx.x;
    int bh = bid & 15;                       // XCD = bid%8 -> K/V L2-resident
    int it = (bid >> 4) & 31;
    int jc = bid >> 9;                       // 0..1
    int i0 = it * 64;
    int b = bh >> 3, par = bh & 1;
    int t = threadIdx.x, rg = t >> 6, lane = t & 63, l = lane & 15, quad = lane >> 4;

    const bf16* Qp = Qg + ((size_t)bh * 2048 + i0 + rg * 16 + l) * 64;
    bf16x8 qf0 = *(const bf16x8*)&Qp[quad * 8];
    bf16x8 qf1 = *(const bf16x8*)&Qp[32 + quad * 8];

    bf16x8 ones;
#pragma unroll
    for (int i = 0; i < 8; ++i) ones[i] = (bf16)1.0f;
    const f32x4 fz = {0.f, 0.f, 0.f, 0.f};

    f32x4 o_acc[4] = {}, l_acc = {};

    int qrow = i0 + rg * 16 + l;
    const unsigned* seqp = pseq + (size_t)b * 131072 + (size_t)qrow * 64;
    const unsigned* sppp = psp + (size_t)par * 131072 + (size_t)qrow * 64;
    const bf16* Kbase = Kg + (size_t)bh * 2048 * 64;
    const bf16* Vbase = Vt + (size_t)bh * 64 * 2048;
    bf16* Pb = P[rg];

    const int NT = 16;
    int jlo = jc * 1024;

    // prologue: stage tile 0; tile 1 issued after tile 0 is consumed-safe
    stage_async(KT[0], Kbase + (size_t)jlo * 64, 64, t);
    stage_async(VT[0], Vbase + jlo, 2048, t);
    bf16x8 pa0, pa1;
    {
        uint2 mseq = *(const uint2*)&seqp[jlo >> 5];
        uint2 msp = *(const uint2*)&sppp[jlo >> 5];
        unsigned w0 = mseq.x & msp.x, w1 = mseq.y & msp.y;
        __syncthreads();                     // K(0),V(0) ready
        stage_async(KT[1], Kbase + (size_t)(jlo + 64) * 64, 64, t);
        stage_async(VT[1], Vbase + (jlo + 64), 2048, t);
        f32x4 s[4];
        __builtin_amdgcn_s_setprio(1);
#pragma unroll
        for (int nc = 0; nc < 4; ++nc) {
            bf16x8 k0f = frag(KT[0], nc * 16 + l, quad);
            bf16x8 k1f = frag(KT[0], nc * 16 + l, 4 + quad);
            s[nc] = MFMA(k0f, qf0, fz);
            s[nc] = MFMA(k1f, qf1, s[nc]);
        }
        __builtin_amdgcn_s_setprio(0);
#pragma unroll
        for (int nc = 0; nc < 4; ++nc) {
            unsigned w = (nc < 2) ? w0 : w1;
            int bbase = (nc & 1) * 16 + quad * 4;
            bf16x4 pv;
#pragma unroll
            for (int r = 0; r < 4; ++r) {
                float e = __builtin_amdgcn_exp2f(s[nc][r]);
                pv[r] = (bf16)(((w >> (bbase + r)) & 1u) ? e : 0.f);
            }
            *(bf16x4*)&Pb[pidx(l, nc * 16 + quad * 4)] = pv;
        }
        pa0 = *(const bf16x8*)&Pb[pidx(l, quad * 8)];
        pa1 = *(const bf16x8*)&Pb[pidx(l, 32 + quad * 8)];
    }

    for (int jj = 1; jj < NT; ++jj) {
        int cur = jj & 1;
        int j0 = jlo + jj * 64;
        uint2 mseq = *(const uint2*)&seqp[j0 >> 5];
        uint2 msp = *(const uint2*)&sppp[j0 >> 5];
        unsigned w0 = mseq.x & msp.x, w1 = mseq.y & msp.y;

        __syncthreads();                     // stage(jj) drained: K(jj),V(jj) ready
        // pre-read V(jj-1) to regs before its buffer is re-staged
        const bf16* Vp = VT[cur ^ 1];
        bf16x8 vr0 = frag(Vp, 0 * 16 + l, quad), vr1 = frag(Vp, 0 * 16 + l, 4 + quad);
        bf16x8 vr2 = frag(Vp, 1 * 16 + l, quad), vr3 = frag(Vp, 1 * 16 + l, 4 + quad);
        bf16x8 vr4 = frag(Vp, 2 * 16 + l, quad), vr5 = frag(Vp, 2 * 16 + l, 4 + quad);
        bf16x8 vr6 = frag(Vp, 3 * 16 + l, quad), vr7 = frag(Vp, 3 * 16 + l, 4 + quad);
        __syncthreads();                     // all waves' V(jj-1) reads complete (WAR)
        if (jj + 1 < NT) {
            stage_async(KT[cur ^ 1], Kbase + (size_t)(j0 + 64) * 64, 64, t);
            stage_async(VT[cur ^ 1], Vbase + (j0 + 64), 2048, t);
        }

        f32x4 s[4];
        __builtin_amdgcn_s_setprio(1);
        // PV(jj-1): pure-register operands, fills MFMA pipe under QK's ds_reads
        l_acc = MFMA(pa0, ones, l_acc);
        l_acc = MFMA(pa1, ones, l_acc);
        o_acc[0] = MFMA(pa0, vr0, o_acc[0]); o_acc[0] = MFMA(pa1, vr1, o_acc[0]);
        o_acc[1] = MFMA(pa0, vr2, o_acc[1]); o_acc[1] = MFMA(pa1, vr3, o_acc[1]);
        o_acc[2] = MFMA(pa0, vr4, o_acc[2]); o_acc[2] = MFMA(pa1, vr5, o_acc[2]);
        o_acc[3] = MFMA(pa0, vr6, o_acc[3]); o_acc[3] = MFMA(pa1, vr7, o_acc[3]);
        // QK(jj)
#pragma unroll
        for (int nc = 0; nc < 4; ++nc) {
            bf16x8 k0f = frag(KT[cur], nc * 16 + l, quad);
            bf16x8 k1f = frag(KT[cur], nc * 16 + l, 4 + quad);
            s[nc] = MFMA(k0f, qf0, fz);
            s[nc] = MFMA(k1f, qf1, s[nc]);
        }
        __builtin_amdgcn_s_setprio(0);

        // softmax(jj) -> P -> pa regs (consumed next iteration)
#pragma unroll
        for (int nc = 0; nc < 4; ++nc) {
            unsigned w = (nc < 2) ? w0 : w1;
            int bbase = (nc & 1) * 16 + quad * 4;
            bf16x4 pv;
#pragma unroll
            for (int r = 0; r < 4; ++r) {
                float e = __builtin_amdgcn_exp2f(s[nc][r]);
                pv[r] = (bf16)(((w >> (bbase + r)) & 1u) ? e : 0.f);
            }
            *(bf16x4*)&Pb[pidx(l, nc * 16 + quad * 4)] = pv;
        }
        pa0 = *(const bf16x8*)&Pb[pidx(l, quad * 8)];
        pa1 = *(const bf16x8*)&Pb[pidx(l, 32 + quad * 8)];
    }

    // epilogue: PV(NT-1); V(NT-1) still in VT[(NT-1)&1] (never overwritten)
    {
        const bf16* Vp = VT[(NT - 1) & 1];
        __builtin_amdgcn_s_setprio(1);
        l_acc = MFMA(pa0, ones, l_acc);
        l_acc = MFMA(pa1, ones, l_acc);
#pragma unroll
        for (int dc = 0; dc < 4; ++dc) {
            bf16x8 vb0 = frag(Vp, dc * 16 + l, quad);
            bf16x8 vb1 = frag(Vp, dc * 16 + l, 4 + quad);
            o_acc[dc] = MFMA(pa0, vb0, o_acc[dc]);
            o_acc[dc] = MFMA(pa1, vb1, o_acc[dc]);
        }
        __builtin_amdgcn_s_setprio(0);
    }

    size_t pb = ((size_t)((bh * 32 + it) * 2 + jc)) * 4096;
#pragma unroll
    for (int dc = 0; dc < 4; ++dc)
#pragma unroll
        for (int r = 0; r < 4; ++r)
            Opart[pb + (size_t)(rg * 16 + quad * 4 + r) * 64 + dc * 16 + l] = o_acc[dc][r];
    if (l == 0) {
#pragma unroll
        for (int r = 0; r < 4; ++r)
            Lpart[((bh * 32 + it) * 2 + jc) * 64 + rg * 16 + quad * 4 + r] = l_acc[r];
    }
}

// ---------------- combine partials -> normalized split-bf16 O (R3-exact, jc=2) -----
__global__ __launch_bounds__(256) void attn_combine(
    const float* __restrict__ Opart, const float* __restrict__ Lpart,
    bf16* __restrict__ Oh, bf16* __restrict__ Ol)
{
    int blk = blockIdx.x;
    int bh = blk >> 5, it = blk & 31;
    int t = threadIdx.x;
    int row = t >> 2, dseg = (t & 3) << 4;

    float acc[16] = {};
    float lsum = 0.f;
#pragma unroll
    for (int jc = 0; jc < 2; ++jc) {
        const float* Op = Opart + ((size_t)(blk * 2 + jc)) * 4096 + (size_t)row * 64 + dseg;
#pragma unroll
        for (int u = 0; u < 4; ++u) {
            float4 v = *(const float4*)&Op[u * 4];
            acc[u * 4 + 0] += v.x; acc[u * 4 + 1] += v.y;
            acc[u * 4 + 2] += v.z; acc[u * 4 + 3] += v.w;
        }
        lsum += Lpart[(blk * 2 + jc) * 64 + row];
    }
    float inv = 1.0f / lsum;
    int b = bh >> 3, h = bh & 7, tok = it * 64 + row;
    size_t base = ((size_t)b * 2048 + tok) * 512 + h * 64 + dseg;
    bf16x8 oh0, oh1, ol0, ol1;
#pragma unroll
    for (int u = 0; u < 8; ++u) {
        float v0 = acc[u] * inv, v1 = acc[8 + u] * inv;
        bf16 h0 = (bf16)v0, h1 = (bf16)v1;
        oh0[u] = h0; ol0[u] = (bf16)(v0 - (float)h0);
        oh1[u] = h1; ol1[u] = (bf16)(v1 - (float)h1);
    }
    *(bf16x8*)&Oh[base] = oh0;
    *(bf16x8*)&Oh[base + 8] = oh1;
    *(bf16x8*)&Ol[base] = ol0;
    *(bf16x8*)&Ol[base + 8] = ol1;
}

// ---------------- output projection, LDS-staged split-bf16 (R3-exact) --------------
__global__ __launch_bounds__(256) void gemm_out(
    const bf16* __restrict__ Ah, const bf16* __restrict__ Al,
    const bf16* __restrict__ Wh, const bf16* __restrict__ Wl,
    float* __restrict__ C)
{
    __shared__ bf16 AhT[4096], AlT[4096], WhT[4096], WlT[4096];
    int bid = blockIdx.x;
    int m0b = bid & 63, n0 = bid >> 6;
    int t = threadIdx.x, wave = t >> 6, lane = t & 63, l = lane & 15, quad = lane >> 4;
    int m0 = m0b * 64 + wave * 16;
    int nb = n0 * 64;
    f32x4 acc[4] = {};
    for (int k0 = 0; k0 < 512; k0 += 64) {
        __syncthreads();
        stage_async(AhT, Ah + (size_t)m0b * 64 * 512 + k0, 512, t);
        stage_async(AlT, Al + (size_t)m0b * 64 * 512 + k0, 512, t);
        stage_async(WhT, Wh + (size_t)nb * 512 + k0, 512, t);
        stage_async(WlT, Wl + (size_t)nb * 512 + k0, 512, t);
        __syncthreads();
        bf16x8 ah0 = frag(AhT, wave * 16 + l, quad);
        bf16x8 ah1 = frag(AhT, wave * 16 + l, 4 + quad);
        bf16x8 al0 = frag(AlT, wave * 16 + l, quad);
        bf16x8 al1 = frag(AlT, wave * 16 + l, 4 + quad);
#pragma unroll
        for (int nc = 0; nc < 4; ++nc) {
            bf16x8 bh0 = frag(WhT, nc * 16 + l, quad);
            bf16x8 bh1 = frag(WhT, nc * 16 + l, 4 + quad);
            bf16x8 bl0 = frag(WlT, nc * 16 + l, quad);
            bf16x8 bl1 = frag(WlT, nc * 16 + l, 4 + quad);
            acc[nc] = MFMA(ah0, bh0, acc[nc]);
            acc[nc] = MFMA(ah1, bh1, acc[nc]);
            acc[nc] = MFMA(ah0, bl0, acc[nc]);
            acc[nc] = MFMA(ah1, bl1, acc[nc]);
            acc[nc] = MFMA(al0, bh0, acc[nc]);
            acc[nc] = MFMA(al1, bh1, acc[nc]);
        }
    }
#pragma unroll
    for (int nc = 0; nc < 4; ++nc)
#pragma unroll
        for (int r = 0; r < 4; ++r)
            C[(size_t)(m0 + quad * 4 + r) * 512 + nb + nc * 16 + l] = acc[nc][r];
}

extern "C" void kernel_launch(void* const* d_in, const int* in_sizes, int n_in,
                              void* d_out, int out_size, void* d_ws, size_t ws_size,
                              hipStream_t stream) {
    const float* x = (const float*)d_in[0];
    const float* Wq = (const float*)d_in[1];
    const float* Wk = (const float*)d_in[2];
    const float* Wv = (const float*)d_in[3];
    const float* Wo = (const float*)d_in[4];
    const int* seqm = (const int*)d_in[5];
    const int* spm = (const int*)d_in[6];
    float* out = (float*)d_out;

    const size_t E = 2097152;            // 2*2048*512
    bf16* xb = (bf16*)d_ws;
    bf16* Wb = xb + E;
    bf16* Woh = Wb + 786432;
    bf16* Wol = Woh + 262144;
    bf16* Qg = Wol + 262144;
    bf16* Kg = Qg + E;
    bf16* Vtg = Kg + E;                  // [bh][64][2048]
    bf16* Ohb = Vtg + E;
    bf16* Olb = Ohb + E;
    unsigned* pseq = (unsigned*)(Olb + E);
    unsigned* psp = pseq + 262144;
    float* Opart = (float*)(psp + 262144);       // 1024 x 4096 fp32 = 16 MB
    float* Lpart = Opart + (size_t)1024 * 4096;  // 0.25 MB

    hipLaunchKernelGGL(prep, dim3(3584), dim3(256), 0, stream,
                       seqm, spm, x, Wq, Wk, Wv, Wo, pseq, psp, xb, Wb, Woh, Wol);
    hipLaunchKernelGGL(gemm_qkv, dim3(768), dim3(256), 0, stream, xb, Wb, Qg, Kg, Vtg);
    hipLaunchKernelGGL(attn_kernel, dim3(1024), dim3(256), 0, stream,
                       Qg, Kg, Vtg, pseq, psp, Opart, Lpart);
    hipLaunchKernelGGL(attn_combine, dim3(512), dim3(256), 0, stream, Opart, Lpart, Ohb, Olb);
    hipLaunchKernelGGL(gemm_out, dim3(512), dim3(256), 0, stream, Ohb, Olb, Woh, Wol, out);
}